// Round 5
// baseline (446.968 us; speedup 1.0000x reference)
//
#include <hip/hip_runtime.h>
#include <hip/hip_bf16.h>

#define NN_ 1024

__device__ __forceinline__ float b2f_(unsigned short u) {
    return __uint_as_float(((unsigned)u) << 16);           // bf16 -> f32, exact
}
__device__ __forceinline__ float ldin(const void* p, int i, int isbf) {
    return isbf ? b2f_(((const unsigned short*)p)[i]) : ((const float*)p)[i];
}
struct f4v { float x, y, z, w; };
__device__ __forceinline__ f4v ldin4(const void* p, int i, int isbf) {   // i % 4 == 0
    f4v r;
    if (isbf) {
        ushort4 u = *(const ushort4*)((const unsigned short*)p + i);
        r.x = b2f_(u.x); r.y = b2f_(u.y); r.z = b2f_(u.z); r.w = b2f_(u.w);
    } else {
        float4 f = *(const float4*)((const float*)p + i);
        r.x = f.x; r.y = f.y; r.z = f.z; r.w = f.w;
    }
    return r;
}

// One block per agent n. Workspace-free: all intermediates live in LDS.
// Output stored as FLOAT32 (reference returns f32; harness reads f32).
__global__ __launch_bounds__(256) void social_lstm_kernel(
        const void* __restrict__ xoff, const void* __restrict__ xabs,
        const void* __restrict__ h0,   const void* __restrict__ c0,
        const void* __restrict__ W_emb, const void* __restrict__ b_emb,
        const void* __restrict__ W_soc, const void* __restrict__ b_soc,
        const void* __restrict__ W_ih,  const void* __restrict__ W_hh,
        const void* __restrict__ b_ih,  const void* __restrict__ b_hh,
        const void* __restrict__ W_out, const void* __restrict__ b_out,
        float* __restrict__ out) {
    __shared__ float s0[8192];       // social tensor, group-0 copy (32 KB)
    __shared__ float s1[8192];       // group-1 copy
    __shared__ int   mlist[NN_];
    __shared__ int   clist[NN_];
    __shared__ int   occ[64];
    __shared__ int   cnt_s;
    __shared__ float xin[128];       // [emb | pool]
    __shared__ float hrow[128];
    __shared__ float gl[512];
    __shared__ float hnl[128];
    __shared__ float red[4][64];

    const int tid = threadIdx.x;
    const int n = blockIdx.x;

    // ---- inline dtype detection (bits[14:7] = bf16 exponent of low half-word;
    //      for f32 data those bits are mantissa noise -> ~15% hit rate) ----
    unsigned wv = ((const unsigned*)W_ih)[tid];
    unsigned e8 = (wv >> 7) & 0xFFu;
    const int isbf = (__syncthreads_count((e8 >= 96u && e8 <= 134u) ? 1 : 0) > 128) ? 1 : 0;

    // ---- init ----
    for (int i = tid; i < 8192; i += 256) { s0[i] = 0.0f; s1[i] = 0.0f; }
    if (tid < 64) occ[tid] = 0;
    if (tid == 0) cnt_s = 0;
    __syncthreads();

    // ---- phase 1: grid_mask replica, compact valid neighbors ----
    float xs = ldin(xabs, 2 * n, isbf)     - 0.2f;   // x[n] - NS/2
    float ys = ldin(xabs, 2 * n + 1, isbf) - 0.2f;
    for (int m = tid; m < NN_; m += 256) {
        float dx = ldin(xabs, 2 * m, isbf)     - xs;
        float dy = ldin(xabs, 2 * m + 1, isbf) - ys;
        int cx = (int)floorf(dx / 0.4f * 8.0f);
        int cy = (int)floorf(dy / 0.4f * 8.0f);
        bool valid = (dx >= 0.0f) && (dx < 0.4f) && (dy >= 0.0f) && (dy < 0.4f)
                  && (cx >= 0) && (cx < 8) && (cy >= 0) && (cy < 8) && (m != n);
        if (valid) {
            int c = cy * 8 + cx;
            int idx = atomicAdd(&cnt_s, 1);
            mlist[idx] = m; clist[idx] = c;
            occ[c] = 1;
        }
    }
    __syncthreads();

    // ---- phase 2: s[c,h] += h0[m,h] over valid m (2 groups, private copies) ----
    {
        const int grp = tid >> 7, hh = tid & 127;
        float* sg = grp ? s1 : s0;
        const int cc = cnt_s;
        for (int i = grp; i < cc; i += 2) {
            int m = mlist[i], c = clist[i];          // wave-uniform
            sg[c * 128 + hh] += ldin(h0, m * 128 + hh, isbf);
        }
    }
    __syncthreads();

    // ---- phase 3: pool[e] = sum_{g occ} sum_h s[g,h] * W_soc[e, g*128+h] ----
    {
        const int e = tid & 63, q = tid >> 6;
        float acc = 0.0f;
        for (int g = 0; g < 64; g++) {
            if (!occ[g]) continue;                   // wave-uniform skip
            int base = g * 128 + q * 32;
#pragma unroll
            for (int h = 0; h < 32; h += 4) {
                f4v w = ldin4(W_soc, e * 8192 + base + h, isbf);
                float v0 = s0[base + h]     + s1[base + h];
                float v1 = s0[base + h + 1] + s1[base + h + 1];
                float v2 = s0[base + h + 2] + s1[base + h + 2];
                float v3 = s0[base + h + 3] + s1[base + h + 3];
                acc = fmaf(v0, w.x, acc); acc = fmaf(v1, w.y, acc);
                acc = fmaf(v2, w.z, acc); acc = fmaf(v3, w.w, acc);
            }
        }
        red[q][e] = acc;
    }
    __syncthreads();
    if (tid < 64) {
        float pl = red[0][tid] + red[1][tid] + red[2][tid] + red[3][tid]
                 + ldin(b_soc, tid, isbf);
        xin[64 + tid] = fmaxf(pl, 0.0f);             // pool half
        float v = fmaf(ldin(xoff, 2 * n, isbf),     ldin(W_emb, 2 * tid, isbf),
                  fmaf(ldin(xoff, 2 * n + 1, isbf), ldin(W_emb, 2 * tid + 1, isbf),
                       ldin(b_emb, tid, isbf)));
        xin[tid] = fmaxf(v, 0.0f);                   // emb half
    } else if (tid >= 128) {
        hrow[tid - 128] = ldin(h0, n * 128 + (tid - 128), isbf);
    }
    __syncthreads();

    // ---- phase 4: gates[j] = xin.W_ih[j,:] + h.W_hh[j,:] + b_ih + b_hh ----
    {
        const int j0 = tid, j1 = tid + 256;
        float a0 = 0.0f, a1 = 0.0f;
        for (int k = 0; k < 128; k += 4) {
            f4v wi0 = ldin4(W_ih, j0 * 128 + k, isbf);
            f4v wh0 = ldin4(W_hh, j0 * 128 + k, isbf);
            f4v wi1 = ldin4(W_ih, j1 * 128 + k, isbf);
            f4v wh1 = ldin4(W_hh, j1 * 128 + k, isbf);
            float x0 = xin[k], x1 = xin[k + 1], x2 = xin[k + 2], x3 = xin[k + 3];
            float h0v = hrow[k], h1v = hrow[k + 1], h2v = hrow[k + 2], h3v = hrow[k + 3];
            a0 = fmaf(x0, wi0.x, a0); a0 = fmaf(x1, wi0.y, a0);
            a0 = fmaf(x2, wi0.z, a0); a0 = fmaf(x3, wi0.w, a0);
            a0 = fmaf(h0v, wh0.x, a0); a0 = fmaf(h1v, wh0.y, a0);
            a0 = fmaf(h2v, wh0.z, a0); a0 = fmaf(h3v, wh0.w, a0);
            a1 = fmaf(x0, wi1.x, a1); a1 = fmaf(x1, wi1.y, a1);
            a1 = fmaf(x2, wi1.z, a1); a1 = fmaf(x3, wi1.w, a1);
            a1 = fmaf(h0v, wh1.x, a1); a1 = fmaf(h1v, wh1.y, a1);
            a1 = fmaf(h2v, wh1.z, a1); a1 = fmaf(h3v, wh1.w, a1);
        }
        gl[j0] = a0 + ldin(b_ih, j0, isbf) + ldin(b_hh, j0, isbf);
        gl[j1] = a1 + ldin(b_ih, j1, isbf) + ldin(b_hh, j1, isbf);
    }
    __syncthreads();

    // ---- phase 5: LSTM pointwise ----
    if (tid < 128) {
        int r = tid;
        float iv = gl[r], fv = gl[r + 128], gv = gl[r + 256], ov = gl[r + 384];
        float si = 1.0f / (1.0f + expf(-iv));
        float sf = 1.0f / (1.0f + expf(-fv));
        float so = 1.0f / (1.0f + expf(-ov));
        float cc = sf * ldin(c0, n * 128 + r, isbf) + si * tanhf(gv);
        hnl[r] = so * tanhf(cc);
    }
    __syncthreads();

    // ---- phase 6: out = hn @ W_out.T + b_out; d_out = [6][1024][20] f32 ----
    if (tid < 120) {
        float acc = ldin(b_out, tid, isbf);
        for (int r = 0; r < 128; r += 4) {
            f4v w = ldin4(W_out, tid * 128 + r, isbf);
            acc = fmaf(hnl[r],     w.x, acc);
            acc = fmaf(hnl[r + 1], w.y, acc);
            acc = fmaf(hnl[r + 2], w.z, acc);
            acc = fmaf(hnl[r + 3], w.w, acc);
        }
        int ch = tid / 20, wc = tid - ch * 20;
        out[ch * 20480 + n * 20 + wc] = acc;         // FLOAT32 store
    }
}

extern "C" void kernel_launch(void* const* d_in, const int* in_sizes, int n_in,
                              void* d_out, int out_size, void* d_ws, size_t ws_size,
                              hipStream_t stream) {
    // d_ws deliberately unused (ws_size evidence from rounds 1-3 says it may be small).
    social_lstm_kernel<<<NN_, 256, 0, stream>>>(
        d_in[0], d_in[1], d_in[2], d_in[3], d_in[4], d_in[5], d_in[6],
        d_in[7], d_in[8], d_in[9], d_in[10], d_in[11], d_in[12], d_in[13],
        (float*)d_out);
}

// Round 6
// 194.119 us; speedup vs baseline: 2.3025x; 2.3025x over previous
//
#include <hip/hip_runtime.h>
#include <hip/hip_bf16.h>

#define NN_ 1024

// ws layout (float-element offsets)
#define OFF_POOL 0        // 65536 f32: pool_raw[n][e] (pre-bias, pre-relu)
#define OFF_P    65536    // C*4096 f32: P chunk (C rows from ws_size)
// min ws = 65536*4 + 32*4096*4 = 768 KB

__device__ __forceinline__ float b2f_(unsigned short u) {
    return __uint_as_float(((unsigned)u) << 16);           // bf16 -> f32, exact
}
__device__ __forceinline__ float ldin(const void* p, int i, int isbf) {
    return isbf ? b2f_(((const unsigned short*)p)[i]) : ((const float*)p)[i];
}
struct f4v { float x, y, z, w; };
__device__ __forceinline__ f4v ldin4(const void* p, int i, int isbf) {   // i % 4 == 0
    f4v r;
    if (isbf) {
        ushort4 u = *(const ushort4*)((const unsigned short*)p + i);
        r.x = b2f_(u.x); r.y = b2f_(u.y); r.z = b2f_(u.z); r.w = b2f_(u.w);
    } else {
        float4 f = *(const float4*)((const float*)p + i);
        r.x = f.x; r.y = f.y; r.z = f.z; r.w = f.w;
    }
    return r;
}
// inline dtype detect: bits[14:7] of a 32b word = bf16 exponent of low half if
// bf16 (sigma=0.05 normals -> ~always in [96,134]); mantissa noise if f32 (~15%).
__device__ __forceinline__ int detect_bf16(const void* Wih, int tid) {
    unsigned wv = ((const unsigned*)Wih)[tid];
    unsigned e8 = (wv >> 7) & 0xFFu;
    return (__syncthreads_count((e8 >= 96u && e8 <= 134u) ? 1 : 0) > 128) ? 1 : 0;
}

// ---- K1: P[mloc, g*64+e] = sum_h h0[m0+mloc, h] * W_soc[e, g*128+h] ----
// block = (g, 32-row m-tile). W_soc g-slice staged via LDS (stride-65 pad,
// lanes e at fixed h -> 2-way bank alias = free). h0 reads wave-uniform scalar.
__global__ __launch_bounds__(256) void pgemm_kernel(const void* __restrict__ Wsoc,
                                                    const void* __restrict__ h0,
                                                    const void* __restrict__ Wih_det,
                                                    float* __restrict__ ws, int m0) {
    __shared__ float Bs[128 * 65];
    const int tid = threadIdx.x;
    const int isbf = detect_bf16(Wih_det, tid);
    const int g = blockIdx.x, mt = blockIdx.y * 32;
    if (isbf) {
        const unsigned short* W = (const unsigned short*)Wsoc;
        for (int i = tid * 4; i < 8192; i += 1024) {
            int e = i >> 7, h = i & 127;
            ushort4 u = *(const ushort4*)(W + e * 8192 + g * 128 + h);
            Bs[(h + 0) * 65 + e] = b2f_(u.x); Bs[(h + 1) * 65 + e] = b2f_(u.y);
            Bs[(h + 2) * 65 + e] = b2f_(u.z); Bs[(h + 3) * 65 + e] = b2f_(u.w);
        }
    } else {
        const float* W = (const float*)Wsoc;
        for (int i = tid * 4; i < 8192; i += 1024) {
            int e = i >> 7, h = i & 127;
            float4 f = *(const float4*)(W + e * 8192 + g * 128 + h);
            Bs[(h + 0) * 65 + e] = f.x; Bs[(h + 1) * 65 + e] = f.y;
            Bs[(h + 2) * 65 + e] = f.z; Bs[(h + 3) * 65 + e] = f.w;
        }
    }
    __syncthreads();
    const int e  = tid & 63;
    const int mq = __builtin_amdgcn_readfirstlane(tid >> 6);   // wave-uniform -> SGPR
    const int mbase = m0 + mt + mq * 8;
    float acc[8];
#pragma unroll
    for (int i = 0; i < 8; i++) acc[i] = 0.0f;
    if (isbf) {
        const unsigned short* H = (const unsigned short*)h0;
        for (int h = 0; h < 128; h += 4) {
            float w0 = Bs[(h + 0) * 65 + e], w1 = Bs[(h + 1) * 65 + e];
            float w2 = Bs[(h + 2) * 65 + e], w3 = Bs[(h + 3) * 65 + e];
#pragma unroll
            for (int mm = 0; mm < 8; mm++) {
                ushort4 u = *(const ushort4*)(H + (mbase + mm) * 128 + h);
                acc[mm] = fmaf(b2f_(u.x), w0, acc[mm]);
                acc[mm] = fmaf(b2f_(u.y), w1, acc[mm]);
                acc[mm] = fmaf(b2f_(u.z), w2, acc[mm]);
                acc[mm] = fmaf(b2f_(u.w), w3, acc[mm]);
            }
        }
    } else {
        const float* H = (const float*)h0;
        for (int h = 0; h < 128; h += 4) {
            float w0 = Bs[(h + 0) * 65 + e], w1 = Bs[(h + 1) * 65 + e];
            float w2 = Bs[(h + 2) * 65 + e], w3 = Bs[(h + 3) * 65 + e];
#pragma unroll
            for (int mm = 0; mm < 8; mm++) {
                float4 f = *(const float4*)(H + (mbase + mm) * 128 + h);
                acc[mm] = fmaf(f.x, w0, acc[mm]); acc[mm] = fmaf(f.y, w1, acc[mm]);
                acc[mm] = fmaf(f.z, w2, acc[mm]); acc[mm] = fmaf(f.w, w3, acc[mm]);
            }
        }
    }
    float* P = ws + OFF_P;
#pragma unroll
    for (int mm = 0; mm < 8; mm++)
        P[(mt + mq * 8 + mm) * 4096 + g * 64 + e] = acc[mm];
}

// ---- K2: pool_raw[n,e] += sum_{valid m in chunk} P[mloc, cell(n,m)*64+e] ----
__global__ __launch_bounds__(256) void pool_kernel(const void* __restrict__ xabs,
                                                   const void* __restrict__ Wih_det,
                                                   float* __restrict__ ws,
                                                   int m0, int mcount, int first) {
    const float* __restrict__ P = ws + OFF_P;
    float* __restrict__ pool    = ws + OFF_POOL;
    __shared__ int cell[NN_];
    __shared__ float red[4][64];
    const int tid = threadIdx.x;
    const int isbf = detect_bf16(Wih_det, tid);
    const int n = blockIdx.x;
    float xs = ldin(xabs, 2 * n, isbf)     - 0.2f;   // x[n] - NS/2
    float ys = ldin(xabs, 2 * n + 1, isbf) - 0.2f;
    for (int i = tid; i < mcount; i += 256) {
        int m = m0 + i;
        float dx = ldin(xabs, 2 * m, isbf)     - xs;
        float dy = ldin(xabs, 2 * m + 1, isbf) - ys;
        int cx = (int)floorf(dx / 0.4f * 8.0f);
        int cy = (int)floorf(dy / 0.4f * 8.0f);
        bool valid = (dx >= 0.0f) && (dx < 0.4f) && (dy >= 0.0f) && (dy < 0.4f)
                  && (cx >= 0) && (cx < 8) && (cy >= 0) && (cy < 8) && (m != n);
        cell[i] = valid ? (cy * 8 + cx) : -1;
    }
    __syncthreads();
    const int e = tid & 63, q = tid >> 6;
    float acc = 0.0f;
    for (int i = q; i < mcount; i += 4) {
        int c = cell[i];                              // wave-uniform
        if (c >= 0) acc += P[i * 4096 + (c << 6) + e];
    }
    red[q][e] = acc;
    __syncthreads();
    if (tid < 64) {
        float s = red[0][tid] + red[1][tid] + red[2][tid] + red[3][tid];
        if (!first) s += pool[n * 64 + tid];
        pool[n * 64 + tid] = s;
    }
}

// ---- K3: emb + gates + LSTM pointwise + output projection (4 agents/block) ----
__global__ __launch_bounds__(256) void lstm_out_kernel(
        const void* __restrict__ xoff, const void* __restrict__ h0,
        const void* __restrict__ c0,   const void* __restrict__ W_emb,
        const void* __restrict__ b_emb, const void* __restrict__ b_soc,
        const void* __restrict__ W_ih, const void* __restrict__ W_hh,
        const void* __restrict__ b_ih, const void* __restrict__ b_hh,
        const void* __restrict__ W_out, const void* __restrict__ b_out,
        const float* __restrict__ ws, float* __restrict__ out) {
    __shared__ float xin[4][128];
    __shared__ float hs[4][128];
    __shared__ float gl[4][512];
    __shared__ float hnl[4][128];
    const int tid = threadIdx.x;
    const int isbf = detect_bf16(W_ih, tid);
    const int n0 = blockIdx.x * 4;
    {
        int nn = tid >> 6, e = tid & 63, n = n0 + nn;
        float v = fmaf(ldin(xoff, 2 * n, isbf),     ldin(W_emb, 2 * e, isbf),
                  fmaf(ldin(xoff, 2 * n + 1, isbf), ldin(W_emb, 2 * e + 1, isbf),
                       ldin(b_emb, e, isbf)));
        xin[nn][e] = fmaxf(v, 0.0f);
        xin[nn][64 + e] = fmaxf(ws[OFF_POOL + n * 64 + e] + ldin(b_soc, e, isbf), 0.0f);
    }
    for (int i = tid; i < 512; i += 256) {
        int nn = i >> 7, k = i & 127;
        hs[nn][k] = ldin(h0, (n0 + nn) * 128 + k, isbf);
    }
    __syncthreads();
    {
        const int j0 = tid, j1 = tid + 256;
        float a0[4] = {0, 0, 0, 0}, a1[4] = {0, 0, 0, 0};
        for (int k = 0; k < 128; k += 4) {
            f4v wi0 = ldin4(W_ih, j0 * 128 + k, isbf);
            f4v wh0 = ldin4(W_hh, j0 * 128 + k, isbf);
            f4v wi1 = ldin4(W_ih, j1 * 128 + k, isbf);
            f4v wh1 = ldin4(W_hh, j1 * 128 + k, isbf);
#pragma unroll
            for (int nn = 0; nn < 4; nn++) {
                float x0 = xin[nn][k], x1 = xin[nn][k + 1];
                float x2 = xin[nn][k + 2], x3 = xin[nn][k + 3];
                float h0v = hs[nn][k], h1v = hs[nn][k + 1];
                float h2v = hs[nn][k + 2], h3v = hs[nn][k + 3];
                a0[nn] = fmaf(x0, wi0.x, a0[nn]); a0[nn] = fmaf(x1, wi0.y, a0[nn]);
                a0[nn] = fmaf(x2, wi0.z, a0[nn]); a0[nn] = fmaf(x3, wi0.w, a0[nn]);
                a0[nn] = fmaf(h0v, wh0.x, a0[nn]); a0[nn] = fmaf(h1v, wh0.y, a0[nn]);
                a0[nn] = fmaf(h2v, wh0.z, a0[nn]); a0[nn] = fmaf(h3v, wh0.w, a0[nn]);
                a1[nn] = fmaf(x0, wi1.x, a1[nn]); a1[nn] = fmaf(x1, wi1.y, a1[nn]);
                a1[nn] = fmaf(x2, wi1.z, a1[nn]); a1[nn] = fmaf(x3, wi1.w, a1[nn]);
                a1[nn] = fmaf(h0v, wh1.x, a1[nn]); a1[nn] = fmaf(h1v, wh1.y, a1[nn]);
                a1[nn] = fmaf(h2v, wh1.z, a1[nn]); a1[nn] = fmaf(h3v, wh1.w, a1[nn]);
            }
        }
        float bb0 = ldin(b_ih, j0, isbf) + ldin(b_hh, j0, isbf);
        float bb1 = ldin(b_ih, j1, isbf) + ldin(b_hh, j1, isbf);
#pragma unroll
        for (int nn = 0; nn < 4; nn++) {
            gl[nn][j0] = a0[nn] + bb0;
            gl[nn][j1] = a1[nn] + bb1;
        }
    }
    __syncthreads();
    for (int i = tid; i < 512; i += 256) {
        int nn = i >> 7, r = i & 127;
        int n = n0 + nn;
        float iv = gl[nn][r], fv = gl[nn][r + 128], gv = gl[nn][r + 256], ov = gl[nn][r + 384];
        float si = 1.0f / (1.0f + expf(-iv));
        float sf = 1.0f / (1.0f + expf(-fv));
        float so = 1.0f / (1.0f + expf(-ov));
        float cc = sf * ldin(c0, n * 128 + r, isbf) + si * tanhf(gv);
        hnl[nn][r] = so * tanhf(cc);
    }
    __syncthreads();
    for (int i = tid; i < 512; i += 256) {
        int nn = i >> 7, j = i & 127;
        if (j < 120) {
            float acc = ldin(b_out, j, isbf);
            for (int r = 0; r < 128; r += 4) {
                f4v w = ldin4(W_out, j * 128 + r, isbf);
                acc = fmaf(hnl[nn][r],     w.x, acc);
                acc = fmaf(hnl[nn][r + 1], w.y, acc);
                acc = fmaf(hnl[nn][r + 2], w.z, acc);
                acc = fmaf(hnl[nn][r + 3], w.w, acc);
            }
            int ch = j / 20, wc = j - ch * 20;
            out[ch * 20480 + (n0 + nn) * 20 + wc] = acc;   // f32, [6][1024][20]
        }
    }
}

extern "C" void kernel_launch(void* const* d_in, const int* in_sizes, int n_in,
                              void* d_out, int out_size, void* d_ws, size_t ws_size,
                              hipStream_t stream) {
    const void* xoff  = d_in[0];
    const void* xabs  = d_in[1];
    const void* h0    = d_in[2];
    const void* c0    = d_in[3];
    const void* W_emb = d_in[4];
    const void* b_emb = d_in[5];
    const void* W_soc = d_in[6];
    const void* b_soc = d_in[7];
    const void* W_ih  = d_in[8];
    const void* W_hh  = d_in[9];
    const void* b_ih  = d_in[10];
    const void* b_hh  = d_in[11];
    const void* W_out = d_in[12];
    const void* b_out = d_in[13];
    float* ws = (float*)d_ws;
    float* out = (float*)d_out;

    // P-chunk rows from ws_size (deterministic -> graph-capture safe)
    long long avail = (long long)(ws_size / 4) - (long long)OFF_P;
    long long cll = avail / 4096;
    int C = (cll > 1024) ? 1024 : (int)cll;
    C &= ~31;
    if (C < 32) C = 32;

    for (int m0 = 0; m0 < NN_; m0 += C) {
        int cnt = (NN_ - m0 < C) ? (NN_ - m0) : C;
        pgemm_kernel<<<dim3(64, cnt / 32), 256, 0, stream>>>(W_soc, h0, W_ih, ws, m0);
        pool_kernel<<<NN_, 256, 0, stream>>>(xabs, W_ih, ws, m0, cnt, m0 == 0 ? 1 : 0);
    }
    lstm_out_kernel<<<256, 256, 0, stream>>>(xoff, h0, c0, W_emb, b_emb, b_soc,
                                             W_ih, W_hh, b_ih, b_hh, W_out, b_out,
                                             ws, out);
}

// Round 7
// 191.790 us; speedup vs baseline: 2.3305x; 1.0121x over previous
//
#include <hip/hip_runtime.h>
#include <hip/hip_bf16.h>

#define NN_ 1024

// ws layout:
//   ushort offsets: WIHT16 @0 (65536: [k][j] 128x512), WHHT16 @65536 (65536),
//                   WOUT16 @131072 (16384: [r][j] 128x128, j>=120 padded 0)
//   float  offsets: OFF_POOL @73728 (65536: pool_raw[n][e])
//   ushort offset : OFF_P16 @278528 (C*4096: P chunk, bf16)
#define U_WIHT   0
#define U_WHHT   65536
#define U_WOUT   131072
#define OFF_POOL 73728
#define U_P      278528

__device__ __forceinline__ float b2f_(unsigned short u) {
    return __uint_as_float(((unsigned)u) << 16);           // bf16 -> f32, exact
}
__device__ __forceinline__ unsigned short f2bu(float f) {  // f32 -> bf16 bits (RNE)
    __hip_bfloat16 b = __float2bfloat16(f);
    return *(unsigned short*)&b;
}
__device__ __forceinline__ float ldin(const void* p, int i, int isbf) {
    return isbf ? b2f_(((const unsigned short*)p)[i]) : ((const float*)p)[i];
}
// inline dtype detect: bits[14:7] of a 32b word = bf16 exponent of low half if
// bf16 (sigma=0.05 normals -> ~always in [96,134]); mantissa noise if f32 (~15%).
__device__ __forceinline__ int detect_bf16(const void* Wih, int tid) {
    unsigned wv = ((const unsigned*)Wih)[tid];
    unsigned e8 = (wv >> 7) & 0xFFu;
    return (__syncthreads_count((e8 >= 96u && e8 <= 134u) ? 1 : 0) > 128) ? 1 : 0;
}

// ---- K1: P[mloc, g*64+e] = sum_h h0[m0+mloc, h] * W_soc[e, g*128+h], bf16 out ----
// block = (g, 64-row m-tile). W_soc g-slice LDS-transposed (stride 65: lanes at
// fixed h -> 2-way bank alias = free). h0 reads wave-uniform (scalar-loadable).
__global__ __launch_bounds__(256) void pgemm_kernel(const void* __restrict__ Wsoc,
                                                    const void* __restrict__ h0,
                                                    const void* __restrict__ Wih_det,
                                                    float* __restrict__ ws, int m0) {
    __shared__ float Bs[128 * 65];
    const int tid = threadIdx.x;
    const int isbf = detect_bf16(Wih_det, tid);
    const int g = blockIdx.x, mt = blockIdx.y * 64;
    if (isbf) {
        const unsigned short* W = (const unsigned short*)Wsoc;
        for (int i = tid * 4; i < 8192; i += 1024) {
            int e = i >> 7, h = i & 127;
            ushort4 u = *(const ushort4*)(W + e * 8192 + g * 128 + h);
            Bs[(h + 0) * 65 + e] = b2f_(u.x); Bs[(h + 1) * 65 + e] = b2f_(u.y);
            Bs[(h + 2) * 65 + e] = b2f_(u.z); Bs[(h + 3) * 65 + e] = b2f_(u.w);
        }
    } else {
        const float* W = (const float*)Wsoc;
        for (int i = tid * 4; i < 8192; i += 1024) {
            int e = i >> 7, h = i & 127;
            float4 f = *(const float4*)(W + e * 8192 + g * 128 + h);
            Bs[(h + 0) * 65 + e] = f.x; Bs[(h + 1) * 65 + e] = f.y;
            Bs[(h + 2) * 65 + e] = f.z; Bs[(h + 3) * 65 + e] = f.w;
        }
    }
    __syncthreads();
    const int e  = tid & 63;
    const int mq = __builtin_amdgcn_readfirstlane(tid >> 6);   // wave-uniform
    const int mbase = m0 + mt + mq * 16;
    float acc[16];
#pragma unroll
    for (int i = 0; i < 16; i++) acc[i] = 0.0f;
    if (isbf) {
        const unsigned short* H = (const unsigned short*)h0;
        for (int h = 0; h < 128; h += 4) {
            float w0 = Bs[(h + 0) * 65 + e], w1 = Bs[(h + 1) * 65 + e];
            float w2 = Bs[(h + 2) * 65 + e], w3 = Bs[(h + 3) * 65 + e];
#pragma unroll
            for (int mm = 0; mm < 16; mm++) {
                ushort4 u = *(const ushort4*)(H + (mbase + mm) * 128 + h);
                acc[mm] = fmaf(b2f_(u.x), w0, acc[mm]);
                acc[mm] = fmaf(b2f_(u.y), w1, acc[mm]);
                acc[mm] = fmaf(b2f_(u.z), w2, acc[mm]);
                acc[mm] = fmaf(b2f_(u.w), w3, acc[mm]);
            }
        }
    } else {
        const float* H = (const float*)h0;
        for (int h = 0; h < 128; h += 4) {
            float w0 = Bs[(h + 0) * 65 + e], w1 = Bs[(h + 1) * 65 + e];
            float w2 = Bs[(h + 2) * 65 + e], w3 = Bs[(h + 3) * 65 + e];
#pragma unroll
            for (int mm = 0; mm < 16; mm++) {
                float4 f = *(const float4*)(H + (mbase + mm) * 128 + h);
                acc[mm] = fmaf(f.x, w0, acc[mm]); acc[mm] = fmaf(f.y, w1, acc[mm]);
                acc[mm] = fmaf(f.z, w2, acc[mm]); acc[mm] = fmaf(f.w, w3, acc[mm]);
            }
        }
    }
    unsigned short* P16 = (unsigned short*)ws + U_P;
#pragma unroll
    for (int mm = 0; mm < 16; mm++)
        P16[(mt + mq * 16 + mm) * 4096 + g * 64 + e] = f2bu(acc[mm]);
}

// ---- K2: pool_raw[n,e] += sum_{valid m in chunk} P[mloc, cell(n,m)*64+e] ----
// First-chunk blocks 0..143 also build the bf16 weight transposes (for K3).
__global__ __launch_bounds__(256) void pool_kernel(const void* __restrict__ xabs,
                                                   const void* __restrict__ Wih,
                                                   const void* __restrict__ Whh,
                                                   const void* __restrict__ Wout,
                                                   float* __restrict__ ws,
                                                   int m0, int mcount, int first) {
    __shared__ int cell[NN_];
    __shared__ float red[4][64];
    const int tid = threadIdx.x;
    const int isbf = detect_bf16(Wih, tid);
    const int n = blockIdx.x;

    if (first && blockIdx.x < 144) {       // fold weight transposes into chunk 0
        unsigned short* u16 = (unsigned short*)ws;
        int base = blockIdx.x * 1024;
        for (int i = tid; i < 1024; i += 256) {
            int t = base + i;
            float v;
            if (t < 65536)       { int k = t >> 9, j = t & 511;       v = ldin(Wih, j * 128 + k, isbf); }
            else if (t < 131072) { int t2 = t - 65536; int k = t2 >> 9, j = t2 & 511; v = ldin(Whh, j * 128 + k, isbf); }
            else                 { int t2 = t - 131072; int r = t2 >> 7, j = t2 & 127;
                                   v = (j < 120) ? ldin(Wout, j * 128 + r, isbf) : 0.0f; }
            u16[t] = f2bu(v);
        }
    }

    float xs = ldin(xabs, 2 * n, isbf)     - 0.2f;   // x[n] - NS/2
    float ys = ldin(xabs, 2 * n + 1, isbf) - 0.2f;
    for (int i = tid; i < mcount; i += 256) {
        int m = m0 + i;
        float dx = ldin(xabs, 2 * m, isbf)     - xs;
        float dy = ldin(xabs, 2 * m + 1, isbf) - ys;
        int cx = (int)floorf(dx / 0.4f * 8.0f);
        int cy = (int)floorf(dy / 0.4f * 8.0f);
        bool valid = (dx >= 0.0f) && (dx < 0.4f) && (dy >= 0.0f) && (dy < 0.4f)
                  && (cx >= 0) && (cx < 8) && (cy >= 0) && (cy < 8) && (m != n);
        cell[i] = valid ? (cy * 8 + cx) : -1;
    }
    __syncthreads();
    const unsigned short* P16 = (const unsigned short*)ws + U_P;
    const int e = tid & 63, q = tid >> 6;
    float acc = 0.0f;
    for (int i = q; i < mcount; i += 4) {
        int c = cell[i];                              // wave-uniform
        if (c >= 0) acc += b2f_(P16[i * 4096 + (c << 6) + e]);
    }
    red[q][e] = acc;
    __syncthreads();
    if (tid < 64) {
        float s = red[0][tid] + red[1][tid] + red[2][tid] + red[3][tid];
        if (!first) s += ws[OFF_POOL + n * 64 + tid];
        ws[OFF_POOL + n * 64 + tid] = s;
    }
}

// ---- K3: emb + gates (coalesced bf16 WT) + LSTM pointwise + out (4 agents/blk) ----
__global__ __launch_bounds__(256) void lstm_out_kernel(
        const void* __restrict__ xoff, const void* __restrict__ h0,
        const void* __restrict__ c0,   const void* __restrict__ W_emb,
        const void* __restrict__ b_emb, const void* __restrict__ b_soc,
        const void* __restrict__ b_ih, const void* __restrict__ b_hh,
        const void* __restrict__ b_out, const void* __restrict__ Wih_det,
        const float* __restrict__ ws, float* __restrict__ out) {
    __shared__ __align__(16) float xin[4][128];
    __shared__ __align__(16) float hs[4][128];
    __shared__ __align__(16) float gl[4][512];
    __shared__ __align__(16) float hnl[4][128];
    const int tid = threadIdx.x;
    const int isbf = detect_bf16(Wih_det, tid);
    const int n0 = blockIdx.x * 4;
    const unsigned short* u16 = (const unsigned short*)ws;
    {
        int nn = tid >> 6, e = tid & 63, n = n0 + nn;
        float v = fmaf(ldin(xoff, 2 * n, isbf),     ldin(W_emb, 2 * e, isbf),
                  fmaf(ldin(xoff, 2 * n + 1, isbf), ldin(W_emb, 2 * e + 1, isbf),
                       ldin(b_emb, e, isbf)));
        xin[nn][e] = fmaxf(v, 0.0f);
        xin[nn][64 + e] = fmaxf(ws[OFF_POOL + n * 64 + e] + ldin(b_soc, e, isbf), 0.0f);
    }
    for (int i = tid; i < 512; i += 256) {
        int nn = i >> 7, k = i & 127;
        hs[nn][k] = ldin(h0, (n0 + nn) * 128 + k, isbf);
    }
    __syncthreads();
    {
        const int j0 = 2 * tid, j1 = 2 * tid + 1;
        float ax[4] = {0, 0, 0, 0}, ay[4] = {0, 0, 0, 0};
        for (int k = 0; k < 128; k += 4) {
            union { float4 v; float f[4]; } xu[4], hu[4];
#pragma unroll
            for (int nn = 0; nn < 4; nn++) {
                xu[nn].v = *(const float4*)&xin[nn][k];
                hu[nn].v = *(const float4*)&hs[nn][k];
            }
#pragma unroll
            for (int kk = 0; kk < 4; kk++) {
                ushort2 wi = *(const ushort2*)(u16 + U_WIHT + (k + kk) * 512 + j0);
                ushort2 wh = *(const ushort2*)(u16 + U_WHHT + (k + kk) * 512 + j0);
                float wix = b2f_(wi.x), wiy = b2f_(wi.y);
                float whx = b2f_(wh.x), why = b2f_(wh.y);
#pragma unroll
                for (int nn = 0; nn < 4; nn++) {
                    float xk = xu[nn].f[kk], hk = hu[nn].f[kk];
                    ax[nn] = fmaf(xk, wix, ax[nn]); ax[nn] = fmaf(hk, whx, ax[nn]);
                    ay[nn] = fmaf(xk, wiy, ay[nn]); ay[nn] = fmaf(hk, why, ay[nn]);
                }
            }
        }
        float bb0 = ldin(b_ih, j0, isbf) + ldin(b_hh, j0, isbf);
        float bb1 = ldin(b_ih, j1, isbf) + ldin(b_hh, j1, isbf);
#pragma unroll
        for (int nn = 0; nn < 4; nn++) {
            gl[nn][j0] = ax[nn] + bb0;
            gl[nn][j1] = ay[nn] + bb1;
        }
    }
    __syncthreads();
    for (int i = tid; i < 512; i += 256) {
        int nn = i >> 7, r = i & 127;
        int n = n0 + nn;
        float iv = gl[nn][r], fv = gl[nn][r + 128], gv = gl[nn][r + 256], ov = gl[nn][r + 384];
        float si = 1.0f / (1.0f + expf(-iv));
        float sf = 1.0f / (1.0f + expf(-fv));
        float so = 1.0f / (1.0f + expf(-ov));
        float cc = sf * ldin(c0, n * 128 + r, isbf) + si * tanhf(gv);
        hnl[nn][r] = so * tanhf(cc);
    }
    __syncthreads();
    for (int i = tid; i < 512; i += 256) {
        int nn = i >> 7, j = i & 127;
        if (j < 120) {
            float acc = ldin(b_out, j, isbf);
            for (int r = 0; r < 128; r += 4) {
                float4 hq = *(const float4*)&hnl[nn][r];
                acc = fmaf(hq.x, b2f_(u16[U_WOUT + (r + 0) * 128 + j]), acc);
                acc = fmaf(hq.y, b2f_(u16[U_WOUT + (r + 1) * 128 + j]), acc);
                acc = fmaf(hq.z, b2f_(u16[U_WOUT + (r + 2) * 128 + j]), acc);
                acc = fmaf(hq.w, b2f_(u16[U_WOUT + (r + 3) * 128 + j]), acc);
            }
            int ch = j / 20, wc = j - ch * 20;
            out[ch * 20480 + (n0 + nn) * 20 + wc] = acc;   // f32, [6][1024][20]
        }
    }
}

extern "C" void kernel_launch(void* const* d_in, const int* in_sizes, int n_in,
                              void* d_out, int out_size, void* d_ws, size_t ws_size,
                              hipStream_t stream) {
    const void* xoff  = d_in[0];
    const void* xabs  = d_in[1];
    const void* h0    = d_in[2];
    const void* c0    = d_in[3];
    const void* W_emb = d_in[4];
    const void* b_emb = d_in[5];
    const void* W_soc = d_in[6];
    const void* b_soc = d_in[7];
    const void* W_ih  = d_in[8];
    const void* W_hh  = d_in[9];
    const void* b_ih  = d_in[10];
    const void* b_hh  = d_in[11];
    const void* W_out = d_in[12];
    const void* b_out = d_in[13];
    float* ws = (float*)d_ws;
    float* out = (float*)d_out;

    // P-chunk rows from ws_size (deterministic -> graph-capture safe)
    long long availu = (long long)(ws_size / 2) - (long long)U_P;
    long long cll = availu / 4096;
    int C = (cll > 1024) ? 1024 : (int)cll;
    C &= ~63;
    if (C < 64) C = 64;     // floor (needs ~1.6 MB ws; round-6 evidence supports)

    for (int m0 = 0; m0 < NN_; m0 += C) {
        int cnt = (NN_ - m0 < C) ? (NN_ - m0) : C;
        pgemm_kernel<<<dim3(64, cnt / 64), 256, 0, stream>>>(W_soc, h0, W_ih, ws, m0);
        pool_kernel<<<NN_, 256, 0, stream>>>(xabs, W_ih, W_hh, W_out, ws, m0, cnt,
                                             m0 == 0 ? 1 : 0);
    }
    lstm_out_kernel<<<256, 256, 0, stream>>>(xoff, h0, c0, W_emb, b_emb, b_soc,
                                             b_ih, b_hh, b_out, W_ih, ws, out);
}

// Round 8
// 182.034 us; speedup vs baseline: 2.4554x; 1.0536x over previous
//
#include <hip/hip_runtime.h>
#include <hip/hip_bf16.h>

#define NN_ 1024

// ws layout:
//   ushort offsets: U_WIHT @0 (65536: [k][j] 128x512), U_WHHT @65536 (65536),
//                   U_WOUT @131072 (16384: [r][j] 128x128, j>=120 padded 0)
//   float  offset : OFF_POOL @73728 (65536: pool_raw[n][e])
//   ushort offset : U_P @278528 (C*4096: P chunk, bf16)
#define U_WIHT   0
#define U_WHHT   65536
#define U_WOUT   131072
#define OFF_POOL 73728
#define U_P      278528

typedef __attribute__((ext_vector_type(8))) short short8;
typedef __attribute__((ext_vector_type(4))) float floatx4;

__device__ __forceinline__ float b2f_(unsigned short u) {
    return __uint_as_float(((unsigned)u) << 16);           // bf16 -> f32, exact
}
__device__ __forceinline__ unsigned short f2bu(float f) {  // f32 -> bf16 bits (RNE)
    __hip_bfloat16 b = __float2bfloat16(f);
    return *(unsigned short*)&b;
}
__device__ __forceinline__ float ldin(const void* p, int i, int isbf) {
    return isbf ? b2f_(((const unsigned short*)p)[i]) : ((const float*)p)[i];
}
// inline dtype detect: bits[14:7] of a 32b word = bf16 exponent of low half if
// bf16 (sigma=0.05 normals -> ~always in [96,134]); mantissa noise if f32 (~15%).
__device__ __forceinline__ int detect_bf16(const void* Wih, int tid) {
    unsigned wv = ((const unsigned*)Wih)[tid];
    unsigned e8 = (wv >> 7) & 0xFFu;
    return (__syncthreads_count((e8 >= 96u && e8 <= 134u) ? 1 : 0) > 128) ? 1 : 0;
}

// ---- K1: P[mloc, g*64+e] = sum_h h0[m0+mloc,h] * W_soc[e, g*128+h], bf16 out ----
// bf16 path: pure MFMA, no LDS. Block = 16 m-rows x 256 cols (4 waves x 64 cols).
// A-frag: h0[m, k..k+7] contiguous; B-frag: W_soc[e, g*128+k..k+7] contiguous.
// f32 path: round-7 LDS-staged VALU fallback (g = blockIdx.x, 64-row tiles).
__global__ __launch_bounds__(256) void pgemm_kernel(const void* __restrict__ Wsoc,
                                                    const void* __restrict__ h0,
                                                    const void* __restrict__ Wih_det,
                                                    float* __restrict__ ws,
                                                    int m0, int mcnt) {
    __shared__ float Bs[128 * 65];
    const int tid = threadIdx.x;
    const int isbf = detect_bf16(Wih_det, tid);
    unsigned short* P16 = (unsigned short*)ws + U_P;

    if (isbf) {
        const short* H = (const short*)h0;
        const short* W = (const short*)Wsoc;
        const int lane = tid & 63;
        const int wv   = tid >> 6;                 // wave 0..3
        const int B    = blockIdx.y * 64 + blockIdx.x;   // 0..mcnt-1
        const int mtiles = mcnt >> 4;
        const int mtile  = B % mtiles;
        const int cg     = B / mtiles;             // 0..15 (256-col group)
        const int m  = lane & 15;
        const int q  = lane >> 4;
        const int mg = m0 + mtile * 16 + m;        // global A row
        const short* Ha = H + mg * 128 + q * 8;
        short8 a0 = *(const short8*)(Ha +  0);
        short8 a1 = *(const short8*)(Ha + 32);
        short8 a2 = *(const short8*)(Ha + 64);
        short8 a3 = *(const short8*)(Ha + 96);
        const int rowl = mtile * 16 + q * 4;       // local P row base
#pragma unroll
        for (int t = 0; t < 4; t++) {
            int n0 = cg * 256 + wv * 64 + t * 16;
            int nc = n0 + m;                       // this lane's B column
            int e  = nc & 63, g = nc >> 6;         // g wave-uniform (16 | n0)
            const short* Wb = W + e * 8192 + g * 128 + q * 8;
            short8 b0 = *(const short8*)(Wb +  0);
            short8 b1 = *(const short8*)(Wb + 32);
            short8 b2 = *(const short8*)(Wb + 64);
            short8 b3 = *(const short8*)(Wb + 96);
            floatx4 c = {0.0f, 0.0f, 0.0f, 0.0f};
            c = __builtin_amdgcn_mfma_f32_16x16x32_bf16(a0, b0, c, 0, 0, 0);
            c = __builtin_amdgcn_mfma_f32_16x16x32_bf16(a1, b1, c, 0, 0, 0);
            c = __builtin_amdgcn_mfma_f32_16x16x32_bf16(a2, b2, c, 0, 0, 0);
            c = __builtin_amdgcn_mfma_f32_16x16x32_bf16(a3, b3, c, 0, 0, 0);
#pragma unroll
            for (int r = 0; r < 4; r++)            // C: col=lane&15, row=q*4+r
                P16[(rowl + r) * 4096 + n0 + m] = f2bu(c[r]);
        }
        return;
    }

    // ---------------- f32 fallback (round-7 structure) ----------------
    const int g = blockIdx.x, mt = blockIdx.y * 64;
    {
        const float* W = (const float*)Wsoc;
        for (int i = tid * 4; i < 8192; i += 1024) {
            int e = i >> 7, h = i & 127;
            float4 f = *(const float4*)(W + e * 8192 + g * 128 + h);
            Bs[(h + 0) * 65 + e] = f.x; Bs[(h + 1) * 65 + e] = f.y;
            Bs[(h + 2) * 65 + e] = f.z; Bs[(h + 3) * 65 + e] = f.w;
        }
    }
    __syncthreads();
    const int e  = tid & 63;
    const int mq = __builtin_amdgcn_readfirstlane(tid >> 6);
    const int mbase = m0 + mt + mq * 16;
    float acc[16];
#pragma unroll
    for (int i = 0; i < 16; i++) acc[i] = 0.0f;
    const float* H = (const float*)h0;
    for (int h = 0; h < 128; h += 4) {
        float w0 = Bs[(h + 0) * 65 + e], w1 = Bs[(h + 1) * 65 + e];
        float w2 = Bs[(h + 2) * 65 + e], w3 = Bs[(h + 3) * 65 + e];
#pragma unroll
        for (int mm = 0; mm < 16; mm++) {
            float4 f = *(const float4*)(H + (mbase + mm) * 128 + h);
            acc[mm] = fmaf(f.x, w0, acc[mm]); acc[mm] = fmaf(f.y, w1, acc[mm]);
            acc[mm] = fmaf(f.z, w2, acc[mm]); acc[mm] = fmaf(f.w, w3, acc[mm]);
        }
    }
#pragma unroll
    for (int mm = 0; mm < 16; mm++)
        P16[(mt + mq * 16 + mm) * 4096 + g * 64 + e] = f2bu(acc[mm]);
}

// ---- K2: pool_raw[n,e] += sum_{valid m in chunk} P[mloc, cell(n,m)*64+e] ----
// ushort2 gathers (lane pair covers 2 e), 8 m-streams. First-chunk blocks
// 0..143 also build the bf16 weight transposes for K3.
__global__ __launch_bounds__(256) void pool_kernel(const void* __restrict__ xabs,
                                                   const void* __restrict__ Wih,
                                                   const void* __restrict__ Whh,
                                                   const void* __restrict__ Wout,
                                                   float* __restrict__ ws,
                                                   int m0, int mcount, int first) {
    __shared__ int cell[NN_];
    __shared__ float2 red[8][32];
    const int tid = threadIdx.x;
    const int isbf = detect_bf16(Wih, tid);
    const int n = blockIdx.x;

    if (first && blockIdx.x < 144) {       // fold weight transposes into chunk 0
        unsigned short* u16 = (unsigned short*)ws;
        int base = blockIdx.x * 1024;
        for (int i = tid; i < 1024; i += 256) {
            int t = base + i;
            float v;
            if (t < 65536)       { int k = t >> 9, j = t & 511;       v = ldin(Wih, j * 128 + k, isbf); }
            else if (t < 131072) { int t2 = t - 65536; int k = t2 >> 9, j = t2 & 511; v = ldin(Whh, j * 128 + k, isbf); }
            else                 { int t2 = t - 131072; int r = t2 >> 7, j = t2 & 127;
                                   v = (j < 120) ? ldin(Wout, j * 128 + r, isbf) : 0.0f; }
            u16[t] = f2bu(v);
        }
    }

    float xs = ldin(xabs, 2 * n, isbf)     - 0.2f;   // x[n] - NS/2
    float ys = ldin(xabs, 2 * n + 1, isbf) - 0.2f;
    for (int i = tid; i < mcount; i += 256) {
        int m = m0 + i;
        float dx = ldin(xabs, 2 * m, isbf)     - xs;
        float dy = ldin(xabs, 2 * m + 1, isbf) - ys;
        int cx = (int)floorf(dx / 0.4f * 8.0f);
        int cy = (int)floorf(dy / 0.4f * 8.0f);
        bool valid = (dx >= 0.0f) && (dx < 0.4f) && (dy >= 0.0f) && (dy < 0.4f)
                  && (cx >= 0) && (cx < 8) && (cy >= 0) && (cy < 8) && (m != n);
        cell[i] = valid ? (cy * 8 + cx) : -1;
    }
    __syncthreads();
    const unsigned short* P16 = (const unsigned short*)ws + U_P;
    const int e2 = tid & 31, grp = tid >> 5;         // e = 2*e2, 2*e2+1
    float accx = 0.0f, accy = 0.0f;
    for (int i = grp; i < mcount; i += 8) {
        int c = cell[i];                              // wave-uniform broadcast
        if (c >= 0) {
            ushort2 u = *(const ushort2*)(P16 + i * 4096 + (c << 6) + 2 * e2);
            accx += b2f_(u.x); accy += b2f_(u.y);
        }
    }
    red[grp][e2] = make_float2(accx, accy);
    __syncthreads();
    if (tid < 32) {
        float sx = 0.0f, sy = 0.0f;
#pragma unroll
        for (int g2 = 0; g2 < 8; g2++) { sx += red[g2][tid].x; sy += red[g2][tid].y; }
        if (!first) {
            sx += ws[OFF_POOL + n * 64 + 2 * tid];
            sy += ws[OFF_POOL + n * 64 + 2 * tid + 1];
        }
        ws[OFF_POOL + n * 64 + 2 * tid]     = sx;
        ws[OFF_POOL + n * 64 + 2 * tid + 1] = sy;
    }
}

// ---- K3: emb + gates (coalesced bf16 WT) + LSTM pointwise + out (4 agents/blk) ----
__global__ __launch_bounds__(256) void lstm_out_kernel(
        const void* __restrict__ xoff, const void* __restrict__ h0,
        const void* __restrict__ c0,   const void* __restrict__ W_emb,
        const void* __restrict__ b_emb, const void* __restrict__ b_soc,
        const void* __restrict__ b_ih, const void* __restrict__ b_hh,
        const void* __restrict__ b_out, const void* __restrict__ Wih_det,
        const float* __restrict__ ws, float* __restrict__ out) {
    __shared__ __align__(16) float xin[4][128];
    __shared__ __align__(16) float hs[4][128];
    __shared__ __align__(16) float gl[4][512];
    __shared__ __align__(16) float hnl[4][128];
    const int tid = threadIdx.x;
    const int isbf = detect_bf16(Wih_det, tid);
    const int n0 = blockIdx.x * 4;
    const unsigned short* u16 = (const unsigned short*)ws;
    {
        int nn = tid >> 6, e = tid & 63, n = n0 + nn;
        float v = fmaf(ldin(xoff, 2 * n, isbf),     ldin(W_emb, 2 * e, isbf),
                  fmaf(ldin(xoff, 2 * n + 1, isbf), ldin(W_emb, 2 * e + 1, isbf),
                       ldin(b_emb, e, isbf)));
        xin[nn][e] = fmaxf(v, 0.0f);
        xin[nn][64 + e] = fmaxf(ws[OFF_POOL + n * 64 + e] + ldin(b_soc, e, isbf), 0.0f);
    }
    for (int i = tid; i < 512; i += 256) {
        int nn = i >> 7, k = i & 127;
        hs[nn][k] = ldin(h0, (n0 + nn) * 128 + k, isbf);
    }
    __syncthreads();
    {
        const int j0 = 2 * tid, j1 = 2 * tid + 1;
        float ax[4] = {0, 0, 0, 0}, ay[4] = {0, 0, 0, 0};
        for (int k = 0; k < 128; k += 4) {
            union { float4 v; float f[4]; } xu[4], hu[4];
#pragma unroll
            for (int nn = 0; nn < 4; nn++) {
                xu[nn].v = *(const float4*)&xin[nn][k];
                hu[nn].v = *(const float4*)&hs[nn][k];
            }
#pragma unroll
            for (int kk = 0; kk < 4; kk++) {
                ushort2 wi = *(const ushort2*)(u16 + U_WIHT + (k + kk) * 512 + j0);
                ushort2 wh = *(const ushort2*)(u16 + U_WHHT + (k + kk) * 512 + j0);
                float wix = b2f_(wi.x), wiy = b2f_(wi.y);
                float whx = b2f_(wh.x), why = b2f_(wh.y);
#pragma unroll
                for (int nn = 0; nn < 4; nn++) {
                    float xk = xu[nn].f[kk], hk = hu[nn].f[kk];
                    ax[nn] = fmaf(xk, wix, ax[nn]); ax[nn] = fmaf(hk, whx, ax[nn]);
                    ay[nn] = fmaf(xk, wiy, ay[nn]); ay[nn] = fmaf(hk, why, ay[nn]);
                }
            }
        }
        float bb0 = ldin(b_ih, j0, isbf) + ldin(b_hh, j0, isbf);
        float bb1 = ldin(b_ih, j1, isbf) + ldin(b_hh, j1, isbf);
#pragma unroll
        for (int nn = 0; nn < 4; nn++) {
            gl[nn][j0] = ax[nn] + bb0;
            gl[nn][j1] = ay[nn] + bb1;
        }
    }
    __syncthreads();
    for (int i = tid; i < 512; i += 256) {
        int nn = i >> 7, r = i & 127;
        int n = n0 + nn;
        float iv = gl[nn][r], fv = gl[nn][r + 128], gv = gl[nn][r + 256], ov = gl[nn][r + 384];
        float si = 1.0f / (1.0f + expf(-iv));
        float sf = 1.0f / (1.0f + expf(-fv));
        float so = 1.0f / (1.0f + expf(-ov));
        float cc = sf * ldin(c0, n * 128 + r, isbf) + si * tanhf(gv);
        hnl[nn][r] = so * tanhf(cc);
    }
    __syncthreads();
    for (int i = tid; i < 512; i += 256) {
        int nn = i >> 7, j = i & 127;
        if (j < 120) {
            float acc = ldin(b_out, j, isbf);
            for (int r = 0; r < 128; r += 4) {
                float4 hq = *(const float4*)&hnl[nn][r];
                acc = fmaf(hq.x, b2f_(u16[U_WOUT + (r + 0) * 128 + j]), acc);
                acc = fmaf(hq.y, b2f_(u16[U_WOUT + (r + 1) * 128 + j]), acc);
                acc = fmaf(hq.z, b2f_(u16[U_WOUT + (r + 2) * 128 + j]), acc);
                acc = fmaf(hq.w, b2f_(u16[U_WOUT + (r + 3) * 128 + j]), acc);
            }
            int ch = j / 20, wc = j - ch * 20;
            out[ch * 20480 + (n0 + nn) * 20 + wc] = acc;   // f32, [6][1024][20]
        }
    }
}

extern "C" void kernel_launch(void* const* d_in, const int* in_sizes, int n_in,
                              void* d_out, int out_size, void* d_ws, size_t ws_size,
                              hipStream_t stream) {
    const void* xoff  = d_in[0];
    const void* xabs  = d_in[1];
    const void* h0    = d_in[2];
    const void* c0    = d_in[3];
    const void* W_emb = d_in[4];
    const void* b_emb = d_in[5];
    const void* W_soc = d_in[6];
    const void* b_soc = d_in[7];
    const void* W_ih  = d_in[8];
    const void* W_hh  = d_in[9];
    const void* b_ih  = d_in[10];
    const void* b_hh  = d_in[11];
    const void* W_out = d_in[12];
    const void* b_out = d_in[13];
    float* ws = (float*)d_ws;
    float* out = (float*)d_out;

    // P-chunk rows from ws_size (deterministic -> graph-capture safe)
    long long availu = (long long)(ws_size / 2) - (long long)U_P;
    long long cll = availu / 4096;
    int C = (cll > 1024) ? 1024 : (int)cll;
    C &= ~63;
    if (C < 64) C = 64;

    for (int m0 = 0; m0 < NN_; m0 += C) {
        int cnt = (NN_ - m0 < C) ? (NN_ - m0) : C;
        pgemm_kernel<<<dim3(64, cnt / 64), 256, 0, stream>>>(W_soc, h0, W_ih, ws, m0, cnt);
        pool_kernel<<<NN_, 256, 0, stream>>>(xabs, W_ih, W_hh, W_out, ws, m0, cnt,
                                             m0 == 0 ? 1 : 0);
    }
    lstm_out_kernel<<<256, 256, 0, stream>>>(xoff, h0, c0, W_emb, b_emb, b_soc,
                                             b_ih, b_hh, b_out, W_ih, ws, out);
}

// Round 9
// 150.745 us; speedup vs baseline: 2.9651x; 1.2076x over previous
//
#include <hip/hip_runtime.h>
#include <hip/hip_bf16.h>

#define NN_ 1024

// ws layout (ushort-element offsets unless noted):
//   U_WIHT @0       (65536: WihT[k][j] 128x512, bf16)
//   U_WHHT @65536   (65536: WhhT[k][j])
//   U_WOUT @131072  (16384: WoutT[r][j] 128x128, j>=120 zero)
//   OFF_POOL        (FLOAT offset 73728: pool_raw[n][e], 65536 f32)
//   U_HHI @278528   (131072: bf16 hi of h0 [m][h])
//   U_HLO @409600   (131072: bf16 lo residual of h0)
//   U_SHI @540672   (524288: bf16 hi of W_soc [e][8192])
//   U_SLO @1064960  (524288: bf16 lo residual of W_soc)
//   U_P   @1589248  (C*4096: P chunk, bf16)
#define U_WIHT   0
#define U_WHHT   65536
#define U_WOUT   131072
#define OFF_POOL 73728
#define U_HHI    278528
#define U_HLO    409600
#define U_SHI    540672
#define U_SLO    1064960
#define U_P      1589248

typedef __attribute__((ext_vector_type(8))) short short8;
typedef __attribute__((ext_vector_type(4))) float floatx4;

__device__ __forceinline__ float b2f_(unsigned short u) {
    return __uint_as_float(((unsigned)u) << 16);           // bf16 -> f32, exact
}
__device__ __forceinline__ unsigned short f2bu(float f) {  // f32 -> bf16 bits (RNE)
    __hip_bfloat16 b = __float2bfloat16(f);
    return *(unsigned short*)&b;
}
__device__ __forceinline__ float ldin(const void* p, int i, int isbf) {
    return isbf ? b2f_(((const unsigned short*)p)[i]) : ((const float*)p)[i];
}
// dtype detect (round-8 counters prove f32 on this harness, but keep it robust)
__device__ __forceinline__ int detect_bf16(const void* Wih, int tid) {
    unsigned wv = ((const unsigned*)Wih)[tid];
    unsigned e8 = (wv >> 7) & 0xFFu;
    return (__syncthreads_count((e8 >= 96u && e8 <= 134u) ? 1 : 0) > 128) ? 1 : 0;
}

// ---- K0: split h0 and W_soc into bf16 hi + bf16 lo residual ----
__global__ void prep_kernel(const void* __restrict__ h0,
                            const void* __restrict__ Wsoc,
                            const void* __restrict__ Wih_det,
                            float* __restrict__ ws) {
    const int tid = threadIdx.x;
    const int isbf = detect_bf16(Wih_det, tid);
    unsigned short* u16 = (unsigned short*)ws;
    int t = blockIdx.x * 256 + tid;
    float x; int dhi, dlo;
    if (t < 131072) {
        x = ldin(h0, t, isbf);
        dhi = U_HHI + t; dlo = U_HLO + t;
    } else {
        int t2 = t - 131072;                       // 0..524287
        x = ldin(Wsoc, t2, isbf);
        dhi = U_SHI + t2; dlo = U_SLO + t2;
    }
    unsigned short hi = f2bu(x);
    u16[dhi] = hi;
    u16[dlo] = f2bu(x - b2f_(hi));
}

// ---- K1: P[mloc, g*64+e] = sum_h h0[m,h]*W_soc[e,g*128+h], hi/lo MFMA ----
// Block = 16 m-rows x 256 cols (4 waves x 4 col-tiles of 16). No LDS.
// A: m=lane&15, k=quad*8+j (contiguous 16B); B mirrors with col=lane&15.
// D: col=lane&15, row=quad*4+reg  [HW-verified mappings, learn_hip m89/m120]
__global__ __launch_bounds__(256) void pgemm_kernel(float* __restrict__ ws,
                                                    int m0, int mcnt) {
    const unsigned short* u16 = (const unsigned short*)ws;
    const short* Hhi = (const short*)(u16 + U_HHI);
    const short* Hlo = (const short*)(u16 + U_HLO);
    const short* Shi = (const short*)(u16 + U_SHI);
    const short* Slo = (const short*)(u16 + U_SLO);
    unsigned short* P16 = (unsigned short*)ws + U_P;

    const int tid  = threadIdx.x;
    const int lane = tid & 63;
    const int wv   = tid >> 6;                     // wave 0..3
    const int B    = blockIdx.y * 64 + blockIdx.x; // 0..mcnt-1
    const int mtiles = mcnt >> 4;
    const int mtile  = B % mtiles;
    const int cg     = B / mtiles;                 // 0..15 (256-col group)
    const int m = lane & 15;
    const int q = lane >> 4;
    const int abase = (m0 + mtile * 16 + m) * 128 + q * 8;
    short8 ah[4], al[4];
#pragma unroll
    for (int j = 0; j < 4; j++) {
        ah[j] = *(const short8*)(Hhi + abase + 32 * j);
        al[j] = *(const short8*)(Hlo + abase + 32 * j);
    }
    const int rowl = mtile * 16 + q * 4;
#pragma unroll
    for (int t = 0; t < 4; t++) {
        int n0 = cg * 256 + wv * 64 + t * 16;
        int nc = n0 + m;
        int e  = nc & 63, g = nc >> 6;
        int wb = e * 8192 + g * 128 + q * 8;
        short8 bh[4], bl[4];
#pragma unroll
        for (int j = 0; j < 4; j++) {
            bh[j] = *(const short8*)(Shi + wb + 32 * j);
            bl[j] = *(const short8*)(Slo + wb + 32 * j);
        }
        floatx4 c = {0.0f, 0.0f, 0.0f, 0.0f};
#pragma unroll
        for (int j = 0; j < 4; j++) c = __builtin_amdgcn_mfma_f32_16x16x32_bf16(ah[j], bh[j], c, 0, 0, 0);
#pragma unroll
        for (int j = 0; j < 4; j++) c = __builtin_amdgcn_mfma_f32_16x16x32_bf16(ah[j], bl[j], c, 0, 0, 0);
#pragma unroll
        for (int j = 0; j < 4; j++) c = __builtin_amdgcn_mfma_f32_16x16x32_bf16(al[j], bh[j], c, 0, 0, 0);
#pragma unroll
        for (int r = 0; r < 4; r++)
            P16[(rowl + r) * 4096 + n0 + m] = f2bu(c[r]);
    }
}

// ---- K2: pool_raw[n,e] += sum_{valid m in chunk} P[mloc, cell(n,m)*64+e] ----
// ushort4 gathers (16 lanes cover 64 e), 16 m-streams. First-chunk blocks
// 0..143 also build the bf16 weight transposes for K3.
__global__ __launch_bounds__(256) void pool_kernel(const void* __restrict__ xabs,
                                                   const void* __restrict__ Wih,
                                                   const void* __restrict__ Whh,
                                                   const void* __restrict__ Wout,
                                                   float* __restrict__ ws,
                                                   int m0, int mcount, int first) {
    __shared__ int cell[NN_];
    __shared__ float4 red4[16][16];
    const int tid = threadIdx.x;
    const int isbf = detect_bf16(Wih, tid);
    const int n = blockIdx.x;

    if (first && blockIdx.x < 144) {       // fold weight transposes into chunk 0
        unsigned short* u16 = (unsigned short*)ws;
        int base = blockIdx.x * 1024;
        for (int i = tid; i < 1024; i += 256) {
            int t = base + i;
            float v;
            if (t < 65536)       { int k = t >> 9, j = t & 511;       v = ldin(Wih, j * 128 + k, isbf); }
            else if (t < 131072) { int t2 = t - 65536; int k = t2 >> 9, j = t2 & 511; v = ldin(Whh, j * 128 + k, isbf); }
            else                 { int t2 = t - 131072; int r = t2 >> 7, j = t2 & 127;
                                   v = (j < 120) ? ldin(Wout, j * 128 + r, isbf) : 0.0f; }
            u16[t] = f2bu(v);
        }
    }

    float xs = ldin(xabs, 2 * n, isbf)     - 0.2f;   // x[n] - NS/2
    float ys = ldin(xabs, 2 * n + 1, isbf) - 0.2f;
    for (int i = tid; i < mcount; i += 256) {
        int m = m0 + i;
        float dx = ldin(xabs, 2 * m, isbf)     - xs;
        float dy = ldin(xabs, 2 * m + 1, isbf) - ys;
        int cx = (int)floorf(dx / 0.4f * 8.0f);
        int cy = (int)floorf(dy / 0.4f * 8.0f);
        bool valid = (dx >= 0.0f) && (dx < 0.4f) && (dy >= 0.0f) && (dy < 0.4f)
                  && (cx >= 0) && (cx < 8) && (cy >= 0) && (cy < 8) && (m != n);
        cell[i] = valid ? (cy * 8 + cx) : -1;
    }
    __syncthreads();
    const unsigned short* P16 = (const unsigned short*)ws + U_P;
    const int e4 = tid & 15, strm = tid >> 4;        // e = 4*e4 .. 4*e4+3
    float ax = 0.0f, ay = 0.0f, az = 0.0f, aw = 0.0f;
    for (int i = strm; i < mcount; i += 16) {
        int c = cell[i];
        if (c >= 0) {
            ushort4 u = *(const ushort4*)(P16 + i * 4096 + (c << 6) + 4 * e4);
            ax += b2f_(u.x); ay += b2f_(u.y); az += b2f_(u.z); aw += b2f_(u.w);
        }
    }
    red4[strm][e4] = make_float4(ax, ay, az, aw);
    __syncthreads();
    if (tid < 16) {
        float4 s = make_float4(0.0f, 0.0f, 0.0f, 0.0f);
#pragma unroll
        for (int s16 = 0; s16 < 16; s16++) {
            float4 r = red4[s16][tid];
            s.x += r.x; s.y += r.y; s.z += r.z; s.w += r.w;
        }
        float* pp = ws + OFF_POOL + n * 64 + 4 * tid;
        if (!first) { s.x += pp[0]; s.y += pp[1]; s.z += pp[2]; s.w += pp[3]; }
        *(float4*)pp = s;
    }
}

// ---- K3: emb + gates (coalesced bf16 WT) + LSTM pointwise + out (4 agents/blk) ----
__global__ __launch_bounds__(256) void lstm_out_kernel(
        const void* __restrict__ xoff, const void* __restrict__ h0,
        const void* __restrict__ c0,   const void* __restrict__ W_emb,
        const void* __restrict__ b_emb, const void* __restrict__ b_soc,
        const void* __restrict__ b_ih, const void* __restrict__ b_hh,
        const void* __restrict__ b_out, const void* __restrict__ Wih_det,
        const float* __restrict__ ws, float* __restrict__ out) {
    __shared__ __align__(16) float xin[4][128];
    __shared__ __align__(16) float hs[4][128];
    __shared__ __align__(16) float gl[4][512];
    __shared__ __align__(16) float hnl[4][128];
    const int tid = threadIdx.x;
    const int isbf = detect_bf16(Wih_det, tid);
    const int n0 = blockIdx.x * 4;
    const unsigned short* u16 = (const unsigned short*)ws;
    {
        int nn = tid >> 6, e = tid & 63, n = n0 + nn;
        float v = fmaf(ldin(xoff, 2 * n, isbf),     ldin(W_emb, 2 * e, isbf),
                  fmaf(ldin(xoff, 2 * n + 1, isbf), ldin(W_emb, 2 * e + 1, isbf),
                       ldin(b_emb, e, isbf)));
        xin[nn][e] = fmaxf(v, 0.0f);
        xin[nn][64 + e] = fmaxf(ws[OFF_POOL + n * 64 + e] + ldin(b_soc, e, isbf), 0.0f);
    }
    for (int i = tid; i < 512; i += 256) {
        int nn = i >> 7, k = i & 127;
        hs[nn][k] = ldin(h0, (n0 + nn) * 128 + k, isbf);
    }
    __syncthreads();
    {
        const int j0 = 2 * tid, j1 = 2 * tid + 1;
        float ax[4] = {0, 0, 0, 0}, ay[4] = {0, 0, 0, 0};
        for (int k = 0; k < 128; k += 4) {
            union { float4 v; float f[4]; } xu[4], hu[4];
#pragma unroll
            for (int nn = 0; nn < 4; nn++) {
                xu[nn].v = *(const float4*)&xin[nn][k];
                hu[nn].v = *(const float4*)&hs[nn][k];
            }
#pragma unroll
            for (int kk = 0; kk < 4; kk++) {
                ushort2 wi = *(const ushort2*)(u16 + U_WIHT + (k + kk) * 512 + j0);
                ushort2 wh = *(const ushort2*)(u16 + U_WHHT + (k + kk) * 512 + j0);
                float wix = b2f_(wi.x), wiy = b2f_(wi.y);
                float whx = b2f_(wh.x), why = b2f_(wh.y);
#pragma unroll
                for (int nn = 0; nn < 4; nn++) {
                    float xk = xu[nn].f[kk], hk = hu[nn].f[kk];
                    ax[nn] = fmaf(xk, wix, ax[nn]); ax[nn] = fmaf(hk, whx, ax[nn]);
                    ay[nn] = fmaf(xk, wiy, ay[nn]); ay[nn] = fmaf(hk, why, ay[nn]);
                }
            }
        }
        float bb0 = ldin(b_ih, j0, isbf) + ldin(b_hh, j0, isbf);
        float bb1 = ldin(b_ih, j1, isbf) + ldin(b_hh, j1, isbf);
#pragma unroll
        for (int nn = 0; nn < 4; nn++) {
            gl[nn][j0] = ax[nn] + bb0;
            gl[nn][j1] = ay[nn] + bb1;
        }
    }
    __syncthreads();
    for (int i = tid; i < 512; i += 256) {
        int nn = i >> 7, r = i & 127;
        int n = n0 + nn;
        float iv = gl[nn][r], fv = gl[nn][r + 128], gv = gl[nn][r + 256], ov = gl[nn][r + 384];
        float si = 1.0f / (1.0f + expf(-iv));
        float sf = 1.0f / (1.0f + expf(-fv));
        float so = 1.0f / (1.0f + expf(-ov));
        float cc = sf * ldin(c0, n * 128 + r, isbf) + si * tanhf(gv);
        hnl[nn][r] = so * tanhf(cc);
    }
    __syncthreads();
    for (int i = tid; i < 512; i += 256) {
        int nn = i >> 7, j = i & 127;
        if (j < 120) {
            float acc = ldin(b_out, j, isbf);
            for (int r = 0; r < 128; r += 4) {
                float4 hq = *(const float4*)&hnl[nn][r];
                acc = fmaf(hq.x, b2f_(u16[U_WOUT + (r + 0) * 128 + j]), acc);
                acc = fmaf(hq.y, b2f_(u16[U_WOUT + (r + 1) * 128 + j]), acc);
                acc = fmaf(hq.z, b2f_(u16[U_WOUT + (r + 2) * 128 + j]), acc);
                acc = fmaf(hq.w, b2f_(u16[U_WOUT + (r + 3) * 128 + j]), acc);
            }
            int ch = j / 20, wc = j - ch * 20;
            out[ch * 20480 + (n0 + nn) * 20 + wc] = acc;   // f32, [6][1024][20]
        }
    }
}

extern "C" void kernel_launch(void* const* d_in, const int* in_sizes, int n_in,
                              void* d_out, int out_size, void* d_ws, size_t ws_size,
                              hipStream_t stream) {
    const void* xoff  = d_in[0];
    const void* xabs  = d_in[1];
    const void* h0    = d_in[2];
    const void* c0    = d_in[3];
    const void* W_emb = d_in[4];
    const void* b_emb = d_in[5];
    const void* W_soc = d_in[6];
    const void* b_soc = d_in[7];
    const void* W_ih  = d_in[8];
    const void* W_hh  = d_in[9];
    const void* b_ih  = d_in[10];
    const void* b_hh  = d_in[11];
    const void* W_out = d_in[12];
    const void* b_out = d_in[13];
    float* ws = (float*)d_ws;
    float* out = (float*)d_out;

    // P-chunk rows from ws_size (deterministic -> graph-capture safe).
    // Round 7/8 evidence (WRITE_SIZE=8192KB single pgemm) shows ws >= ~9 MB.
    long long availu = (long long)(ws_size / 2) - (long long)U_P;
    long long cll = availu / 4096;
    int C = (cll > 1024) ? 1024 : (int)cll;
    C &= ~63;
    if (C < 64) C = 64;

    prep_kernel<<<2560, 256, 0, stream>>>(h0, W_soc, W_ih, ws);
    for (int m0 = 0; m0 < NN_; m0 += C) {
        int cnt = (NN_ - m0 < C) ? (NN_ - m0) : C;
        pgemm_kernel<<<dim3(64, cnt / 64), 256, 0, stream>>>(ws, m0, cnt);
        pool_kernel<<<NN_, 256, 0, stream>>>(xabs, W_ih, W_hh, W_out, ws, m0, cnt,
                                             m0 == 0 ? 1 : 0);
    }
    lstm_out_kernel<<<256, 256, 0, stream>>>(xoff, h0, c0, W_emb, b_emb, b_soc,
                                             b_ih, b_hh, b_out, W_ih, ws, out);
}

// Round 10
// 133.940 us; speedup vs baseline: 3.3371x; 1.1255x over previous
//
#include <hip/hip_runtime.h>
#include <hip/hip_bf16.h>

#define NN_ 1024

// ws layout (ushort-element offsets unless noted):
//   U_WIHT @0       (65536: WihT[k][j] 128x512, bf16)
//   U_WHHT @65536   (65536: WhhT[k][j])
//   U_WOUT @131072  (16384: WoutT[r][j] 128x128, j>=120 zero)
//   OFF_POOL        (FLOAT offset 73728: pool_raw[n][e], 65536 f32)
//   U_HHI @278528   (131072: bf16 hi of h0 [m][h])
//   U_HLO @409600   (131072: bf16 lo residual of h0)
//   U_SHI @540672   (524288: bf16 hi of W_soc [e][8192])
//   U_SLO @1064960  (524288: bf16 lo residual of W_soc)
//   U_P   @1589248  (C*4096: P chunk, bf16)
#define U_WIHT   0
#define U_WHHT   65536
#define U_WOUT   131072
#define OFF_POOL 73728
#define U_HHI    278528
#define U_HLO    409600
#define U_SHI    540672
#define U_SLO    1064960
#define U_P      1589248

typedef __attribute__((ext_vector_type(8))) short short8;
typedef __attribute__((ext_vector_type(4))) float floatx4;

__device__ __forceinline__ float b2f_(unsigned short u) {
    return __uint_as_float(((unsigned)u) << 16);           // bf16 -> f32, exact
}
__device__ __forceinline__ unsigned short f2bu(float f) {  // f32 -> bf16 bits (RNE)
    __hip_bfloat16 b = __float2bfloat16(f);
    return *(unsigned short*)&b;
}
__device__ __forceinline__ float ldin(const void* p, int i, int isbf) {
    return isbf ? b2f_(((const unsigned short*)p)[i]) : ((const float*)p)[i];
}
// dtype detect (round-8 counters prove f32 on this harness, but keep it robust)
__device__ __forceinline__ int detect_bf16(const void* Wih, int tid) {
    unsigned wv = ((const unsigned*)Wih)[tid];
    unsigned e8 = (wv >> 7) & 0xFFu;
    return (__syncthreads_count((e8 >= 96u && e8 <= 134u) ? 1 : 0) > 128) ? 1 : 0;
}

// ---- K0: split h0 and W_soc into bf16 hi + bf16 lo residual ----
__global__ void prep_kernel(const void* __restrict__ h0,
                            const void* __restrict__ Wsoc,
                            const void* __restrict__ Wih_det,
                            float* __restrict__ ws) {
    const int tid = threadIdx.x;
    const int isbf = detect_bf16(Wih_det, tid);
    unsigned short* u16 = (unsigned short*)ws;
    int t = blockIdx.x * 256 + tid;
    float x; int dhi, dlo;
    if (t < 131072) {
        x = ldin(h0, t, isbf);
        dhi = U_HHI + t; dlo = U_HLO + t;
    } else {
        int t2 = t - 131072;                       // 0..524287
        x = ldin(Wsoc, t2, isbf);
        dhi = U_SHI + t2; dlo = U_SLO + t2;
    }
    unsigned short hi = f2bu(x);
    u16[dhi] = hi;
    u16[dlo] = f2bu(x - b2f_(hi));
}

// ---- K1: P[mloc, g*64+e] = sum_h h0[m,h]*W_soc[e,g*128+h], hi/lo MFMA ----
// Block = 16 m-rows x 256 cols (4 waves x 4 col-tiles of 16). No LDS.
__global__ __launch_bounds__(256) void pgemm_kernel(float* __restrict__ ws,
                                                    int m0, int mcnt) {
    const unsigned short* u16 = (const unsigned short*)ws;
    const short* Hhi = (const short*)(u16 + U_HHI);
    const short* Hlo = (const short*)(u16 + U_HLO);
    const short* Shi = (const short*)(u16 + U_SHI);
    const short* Slo = (const short*)(u16 + U_SLO);
    unsigned short* P16 = (unsigned short*)ws + U_P;

    const int tid  = threadIdx.x;
    const int lane = tid & 63;
    const int wv   = tid >> 6;                     // wave 0..3
    const int B    = blockIdx.y * 64 + blockIdx.x; // 0..mcnt-1
    const int mtiles = mcnt >> 4;
    const int mtile  = B % mtiles;
    const int cg     = B / mtiles;                 // 0..15 (256-col group)
    const int m = lane & 15;
    const int q = lane >> 4;
    const int abase = (m0 + mtile * 16 + m) * 128 + q * 8;
    short8 ah[4], al[4];
#pragma unroll
    for (int j = 0; j < 4; j++) {
        ah[j] = *(const short8*)(Hhi + abase + 32 * j);
        al[j] = *(const short8*)(Hlo + abase + 32 * j);
    }
    const int rowl = mtile * 16 + q * 4;
#pragma unroll
    for (int t = 0; t < 4; t++) {
        int n0 = cg * 256 + wv * 64 + t * 16;
        int nc = n0 + m;
        int e  = nc & 63, g = nc >> 6;
        int wb = e * 8192 + g * 128 + q * 8;
        short8 bh[4], bl[4];
#pragma unroll
        for (int j = 0; j < 4; j++) {
            bh[j] = *(const short8*)(Shi + wb + 32 * j);
            bl[j] = *(const short8*)(Slo + wb + 32 * j);
        }
        floatx4 c = {0.0f, 0.0f, 0.0f, 0.0f};
#pragma unroll
        for (int j = 0; j < 4; j++) c = __builtin_amdgcn_mfma_f32_16x16x32_bf16(ah[j], bh[j], c, 0, 0, 0);
#pragma unroll
        for (int j = 0; j < 4; j++) c = __builtin_amdgcn_mfma_f32_16x16x32_bf16(ah[j], bl[j], c, 0, 0, 0);
#pragma unroll
        for (int j = 0; j < 4; j++) c = __builtin_amdgcn_mfma_f32_16x16x32_bf16(al[j], bh[j], c, 0, 0, 0);
#pragma unroll
        for (int r = 0; r < 4; r++)
            P16[(rowl + r) * 4096 + n0 + m] = f2bu(c[r]);
    }
}

// ---- K2: pool_raw[n,e] += sum_{valid m} P[mloc, cell(n,m)*64+e] ----
// Compacted offset list (branch-free gather loop, independent iterations).
// First-chunk blocks 0..143 also build the bf16 weight transposes for K3.
__global__ __launch_bounds__(256) void pool_kernel(const void* __restrict__ xabs,
                                                   const void* __restrict__ Wih,
                                                   const void* __restrict__ Whh,
                                                   const void* __restrict__ Wout,
                                                   float* __restrict__ ws,
                                                   int m0, int mcount, int first) {
    __shared__ int off[NN_];          // i*4096 + cell*64 for each valid neighbor
    __shared__ int cnt_s;
    __shared__ float4 red4[16][16];
    const int tid = threadIdx.x;
    const int isbf = detect_bf16(Wih, tid);
    const int n = blockIdx.x;

    if (first && blockIdx.x < 144) {       // fold weight transposes into chunk 0
        unsigned short* u16 = (unsigned short*)ws;
        int base = blockIdx.x * 1024;
        for (int i = tid; i < 1024; i += 256) {
            int t = base + i;
            float v;
            if (t < 65536)       { int k = t >> 9, j = t & 511;       v = ldin(Wih, j * 128 + k, isbf); }
            else if (t < 131072) { int t2 = t - 65536; int k = t2 >> 9, j = t2 & 511; v = ldin(Whh, j * 128 + k, isbf); }
            else                 { int t2 = t - 131072; int r = t2 >> 7, j = t2 & 127;
                                   v = (j < 120) ? ldin(Wout, j * 128 + r, isbf) : 0.0f; }
            u16[t] = f2bu(v);
        }
    }
    if (tid == 0) cnt_s = 0;
    __syncthreads();

    float xs = ldin(xabs, 2 * n, isbf)     - 0.2f;   // x[n] - NS/2
    float ys = ldin(xabs, 2 * n + 1, isbf) - 0.2f;
    for (int i = tid; i < mcount; i += 256) {
        int m = m0 + i;
        float dx = ldin(xabs, 2 * m, isbf)     - xs;
        float dy = ldin(xabs, 2 * m + 1, isbf) - ys;
        int cx = (int)floorf(dx / 0.4f * 8.0f);
        int cy = (int)floorf(dy / 0.4f * 8.0f);
        bool valid = (dx >= 0.0f) && (dx < 0.4f) && (dy >= 0.0f) && (dy < 0.4f)
                  && (cx >= 0) && (cx < 8) && (cy >= 0) && (cy < 8) && (m != n);
        if (valid) {
            int idx = atomicAdd(&cnt_s, 1);
            off[idx] = i * 4096 + ((cy * 8 + cx) << 6);
        }
    }
    __syncthreads();
    const unsigned short* P16 = (const unsigned short*)ws + U_P;
    const int e4 = tid & 15, strm = tid >> 4;        // e = 4*e4 .. 4*e4+3
    const int cc = cnt_s;
    float ax = 0.0f, ay = 0.0f, az = 0.0f, aw = 0.0f;
    for (int j = strm; j < cc; j += 16) {            // branch-free gathers
        int o = off[j];
        ushort4 u = *(const ushort4*)(P16 + o + 4 * e4);
        ax += b2f_(u.x); ay += b2f_(u.y); az += b2f_(u.z); aw += b2f_(u.w);
    }
    red4[strm][e4] = make_float4(ax, ay, az, aw);
    __syncthreads();
    if (tid < 16) {
        float4 s = make_float4(0.0f, 0.0f, 0.0f, 0.0f);
#pragma unroll
        for (int s16 = 0; s16 < 16; s16++) {
            float4 r = red4[s16][tid];
            s.x += r.x; s.y += r.y; s.z += r.z; s.w += r.w;
        }
        float* pp = ws + OFF_POOL + n * 64 + 4 * tid;
        if (!first) { s.x += pp[0]; s.y += pp[1]; s.z += pp[2]; s.w += pp[3]; }
        *(float4*)pp = s;
    }
}

// ---- K3: emb + gates (coalesced bf16 WT) + LSTM pointwise + out (2 agents/blk) ----
__global__ __launch_bounds__(256) void lstm_out_kernel(
        const void* __restrict__ xoff, const void* __restrict__ h0,
        const void* __restrict__ c0,   const void* __restrict__ W_emb,
        const void* __restrict__ b_emb, const void* __restrict__ b_soc,
        const void* __restrict__ b_ih, const void* __restrict__ b_hh,
        const void* __restrict__ b_out, const void* __restrict__ Wih_det,
        const float* __restrict__ ws, float* __restrict__ out) {
    __shared__ __align__(16) float xin[2][128];
    __shared__ __align__(16) float hs[2][128];
    __shared__ __align__(16) float gl[2][512];
    __shared__ __align__(16) float hnl[2][128];
    const int tid = threadIdx.x;
    const int isbf = detect_bf16(Wih_det, tid);
    const int n0 = blockIdx.x * 2;
    const unsigned short* u16 = (const unsigned short*)ws;
    if (tid < 128) {
        int nn = tid >> 6, e = tid & 63, n = n0 + nn;
        float v = fmaf(ldin(xoff, 2 * n, isbf),     ldin(W_emb, 2 * e, isbf),
                  fmaf(ldin(xoff, 2 * n + 1, isbf), ldin(W_emb, 2 * e + 1, isbf),
                       ldin(b_emb, e, isbf)));
        xin[nn][e] = fmaxf(v, 0.0f);
        xin[nn][64 + e] = fmaxf(ws[OFF_POOL + n * 64 + e] + ldin(b_soc, e, isbf), 0.0f);
    } else {
        int t = tid - 128;                 // 0..127 -> hs rows via second pass below
    }
    {
        int nn = tid >> 7, k = tid & 127;
        hs[nn][k] = ldin(h0, (n0 + nn) * 128 + k, isbf);
    }
    __syncthreads();
    {
        const int j0 = 2 * tid, j1 = 2 * tid + 1;
        float ax[2] = {0, 0}, ay[2] = {0, 0};
        for (int k = 0; k < 128; k += 4) {
            union { float4 v; float f[4]; } xu[2], hu[2];
#pragma unroll
            for (int nn = 0; nn < 2; nn++) {
                xu[nn].v = *(const float4*)&xin[nn][k];
                hu[nn].v = *(const float4*)&hs[nn][k];
            }
#pragma unroll
            for (int kk = 0; kk < 4; kk++) {
                ushort2 wi = *(const ushort2*)(u16 + U_WIHT + (k + kk) * 512 + j0);
                ushort2 wh = *(const ushort2*)(u16 + U_WHHT + (k + kk) * 512 + j0);
                float wix = b2f_(wi.x), wiy = b2f_(wi.y);
                float whx = b2f_(wh.x), why = b2f_(wh.y);
#pragma unroll
                for (int nn = 0; nn < 2; nn++) {
                    float xk = xu[nn].f[kk], hk = hu[nn].f[kk];
                    ax[nn] = fmaf(xk, wix, ax[nn]); ax[nn] = fmaf(hk, whx, ax[nn]);
                    ay[nn] = fmaf(xk, wiy, ay[nn]); ay[nn] = fmaf(hk, why, ay[nn]);
                }
            }
        }
        float bb0 = ldin(b_ih, j0, isbf) + ldin(b_hh, j0, isbf);
        float bb1 = ldin(b_ih, j1, isbf) + ldin(b_hh, j1, isbf);
#pragma unroll
        for (int nn = 0; nn < 2; nn++) {
            gl[nn][j0] = ax[nn] + bb0;
            gl[nn][j1] = ay[nn] + bb1;
        }
    }
    __syncthreads();
    {
        int nn = tid >> 7, r = tid & 127;
        int n = n0 + nn;
        float iv = gl[nn][r], fv = gl[nn][r + 128], gv = gl[nn][r + 256], ov = gl[nn][r + 384];
        float si = 1.0f / (1.0f + expf(-iv));
        float sf = 1.0f / (1.0f + expf(-fv));
        float so = 1.0f / (1.0f + expf(-ov));
        float cc = sf * ldin(c0, n * 128 + r, isbf) + si * tanhf(gv);
        hnl[nn][r] = so * tanhf(cc);
    }
    __syncthreads();
    {
        int nn = tid >> 7, j = tid & 127;
        if (j < 120) {
            float acc = ldin(b_out, j, isbf);
            for (int r = 0; r < 128; r += 4) {
                float4 hq = *(const float4*)&hnl[nn][r];
                acc = fmaf(hq.x, b2f_(u16[U_WOUT + (r + 0) * 128 + j]), acc);
                acc = fmaf(hq.y, b2f_(u16[U_WOUT + (r + 1) * 128 + j]), acc);
                acc = fmaf(hq.z, b2f_(u16[U_WOUT + (r + 2) * 128 + j]), acc);
                acc = fmaf(hq.w, b2f_(u16[U_WOUT + (r + 3) * 128 + j]), acc);
            }
            int ch = j / 20, wc = j - ch * 20;
            out[ch * 20480 + (n0 + nn) * 20 + wc] = acc;   // f32, [6][1024][20]
        }
    }
}

extern "C" void kernel_launch(void* const* d_in, const int* in_sizes, int n_in,
                              void* d_out, int out_size, void* d_ws, size_t ws_size,
                              hipStream_t stream) {
    const void* xoff  = d_in[0];
    const void* xabs  = d_in[1];
    const void* h0    = d_in[2];
    const void* c0    = d_in[3];
    const void* W_emb = d_in[4];
    const void* b_emb = d_in[5];
    const void* W_soc = d_in[6];
    const void* b_soc = d_in[7];
    const void* W_ih  = d_in[8];
    const void* W_hh  = d_in[9];
    const void* b_ih  = d_in[10];
    const void* b_hh  = d_in[11];
    const void* W_out = d_in[12];
    const void* b_out = d_in[13];
    float* ws = (float*)d_ws;
    float* out = (float*)d_out;

    // P-chunk rows from ws_size (deterministic -> graph-capture safe)
    long long availu = (long long)(ws_size / 2) - (long long)U_P;
    long long cll = availu / 4096;
    int C = (cll > 1024) ? 1024 : (int)cll;
    C &= ~63;
    if (C < 64) C = 64;

    prep_kernel<<<2560, 256, 0, stream>>>(h0, W_soc, W_ih, ws);
    for (int m0 = 0; m0 < NN_; m0 += C) {
        int cnt = (NN_ - m0 < C) ? (NN_ - m0) : C;
        pgemm_kernel<<<dim3(64, cnt / 64), 256, 0, stream>>>(ws, m0, cnt);
        pool_kernel<<<NN_, 256, 0, stream>>>(xabs, W_ih, W_hh, W_out, ws, m0, cnt,
                                             m0 == 0 ? 1 : 0);
    }
    lstm_out_kernel<<<512, 256, 0, stream>>>(xoff, h0, c0, W_emb, b_emb, b_soc,
                                             b_ih, b_hh, b_out, W_ih, ws, out);
}

// Round 11
// 132.710 us; speedup vs baseline: 3.3680x; 1.0093x over previous
//
#include <hip/hip_runtime.h>
#include <hip/hip_bf16.h>

#define NN_ 1024

// ws layout (ushort-element offsets). ws is 256 MiB (fill evidence, r9/r10).
//   U_WIHT @0      (65536: WihT[k][j] 128x512 bf16)
//   U_WHHT @65536  (65536: WhhT[k][j])
//   U_WOUT @131072 (16384: WoutT[r][j] 128x128, j>=120 zero)
//   U_P    @147456 (1024*4096: P[m][g*64+e] bf16)
#define U_WIHT 0
#define U_WHHT 65536
#define U_WOUT 131072
#define U_P    147456

typedef __attribute__((ext_vector_type(8))) short short8;
typedef __attribute__((ext_vector_type(4))) float floatx4;

__device__ __forceinline__ float b2f_(unsigned short u) {
    return __uint_as_float(((unsigned)u) << 16);           // bf16 -> f32, exact
}
__device__ __forceinline__ unsigned short f2bu(float f) {  // f32 -> bf16 bits (RNE)
    __hip_bfloat16 b = __float2bfloat16(f);
    return *(unsigned short*)&b;
}
__device__ __forceinline__ float ldin(const void* p, int i, int isbf) {
    return isbf ? b2f_(((const unsigned short*)p)[i]) : ((const float*)p)[i];
}
__device__ __forceinline__ int detect_bf16(const void* Wih, int tid) {
    unsigned wv = ((const unsigned*)Wih)[tid];
    unsigned e8 = (wv >> 7) & 0xFFu;
    return (__syncthreads_count((e8 >= 96u && e8 <= 134u) ? 1 : 0) > 128) ? 1 : 0;
}
// split 8 consecutive f32 into bf16 hi + bf16 residual lo fragments
__device__ __forceinline__ void split8f(const float* p, short8& hi, short8& lo) {
    const float4 f0 = *(const float4*)p;
    const float4 f1 = *(const float4*)(p + 4);
    float x[8] = {f0.x, f0.y, f0.z, f0.w, f1.x, f1.y, f1.z, f1.w};
    unsigned short* H = (unsigned short*)&hi;
    unsigned short* L = (unsigned short*)&lo;
#pragma unroll
    for (int i = 0; i < 8; i++) {
        unsigned short h = f2bu(x[i]);
        H[i] = h;
        L[i] = f2bu(x[i] - b2f_(h));
    }
}

// ---- K1: P[m, g*64+e] = sum_h h0[m,h]*W_soc[e,g*128+h] via hi/lo MFMA ----
// Inline f32->hi/lo split (no prep kernel). Blocks B<144 also build the bf16
// weight transposes consumed by K2. Block = 16 m-rows x 256 cols, no LDS use
// beyond detect.  A: m=lane&15, k=quad*8+j; D: col=lane&15, row=quad*4+reg.
__global__ __launch_bounds__(256) void pgemm_kernel(const void* __restrict__ Wsoc,
                                                    const void* __restrict__ h0,
                                                    const void* __restrict__ Wih,
                                                    const void* __restrict__ Whh,
                                                    const void* __restrict__ Wout,
                                                    float* __restrict__ ws) {
    const int tid = threadIdx.x;
    const int isbf = detect_bf16(Wih, tid);
    unsigned short* u16w = (unsigned short*)ws;
    unsigned short* P16  = u16w + U_P;
    const int lane = tid & 63;
    const int wv   = tid >> 6;                     // wave 0..3
    const int B    = blockIdx.y * 64 + blockIdx.x; // 0..1023
    const int mtile = B & 63;
    const int cg    = B >> 6;                      // 0..15 (256-col group)
    const int m = lane & 15;
    const int q = lane >> 4;
    const int abase = (mtile * 16 + m) * 128 + q * 8;
    short8 ah[4], al[4];
    if (isbf) {
        const unsigned short* H = (const unsigned short*)h0;
#pragma unroll
        for (int j = 0; j < 4; j++) {
            ah[j] = *(const short8*)(H + abase + 32 * j);
            al[j] = short8{0, 0, 0, 0, 0, 0, 0, 0};
        }
    } else {
        const float* H = (const float*)h0;
#pragma unroll
        for (int j = 0; j < 4; j++) split8f(H + abase + 32 * j, ah[j], al[j]);
    }
    const int rowl = mtile * 16 + q * 4;
#pragma unroll
    for (int t = 0; t < 4; t++) {
        const int n0 = cg * 256 + wv * 64 + t * 16;
        const int nc = n0 + m;
        const int e = nc & 63, g = nc >> 6;
        const int wb = e * 8192 + g * 128 + q * 8;
        short8 bh[4], bl[4];
        if (isbf) {
            const unsigned short* W = (const unsigned short*)Wsoc;
#pragma unroll
            for (int j = 0; j < 4; j++) {
                bh[j] = *(const short8*)(W + wb + 32 * j);
                bl[j] = short8{0, 0, 0, 0, 0, 0, 0, 0};
            }
        } else {
            const float* W = (const float*)Wsoc;
#pragma unroll
            for (int j = 0; j < 4; j++) split8f(W + wb + 32 * j, bh[j], bl[j]);
        }
        floatx4 c = {0.0f, 0.0f, 0.0f, 0.0f};
#pragma unroll
        for (int j = 0; j < 4; j++) c = __builtin_amdgcn_mfma_f32_16x16x32_bf16(ah[j], bh[j], c, 0, 0, 0);
#pragma unroll
        for (int j = 0; j < 4; j++) c = __builtin_amdgcn_mfma_f32_16x16x32_bf16(ah[j], bl[j], c, 0, 0, 0);
#pragma unroll
        for (int j = 0; j < 4; j++) c = __builtin_amdgcn_mfma_f32_16x16x32_bf16(al[j], bh[j], c, 0, 0, 0);
#pragma unroll
        for (int r = 0; r < 4; r++)
            P16[(rowl + r) * 4096 + n0 + m] = f2bu(c[r]);
    }
    if (B < 144) {                                 // bf16 weight transposes for K2
        int base = B * 1024;
        for (int i = tid; i < 1024; i += 256) {
            int t = base + i;
            float v;
            if (t < 65536)       { int k = t >> 9, j = t & 511;       v = ldin(Wih, j * 128 + k, isbf); }
            else if (t < 131072) { int t2 = t - 65536; int k = t2 >> 9, j = t2 & 511; v = ldin(Whh, j * 128 + k, isbf); }
            else                 { int t2 = t - 131072; int r = t2 >> 7, j = t2 & 127;
                                   v = (j < 120) ? ldin(Wout, j * 128 + r, isbf) : 0.0f; }
            u16w[t] = f2bu(v);
        }
    }
}

// ---- K2: fused pool + emb + gates + LSTM pointwise + output (2 agents/block) ----
__global__ __launch_bounds__(256) void pool_lstm_kernel(
        const void* __restrict__ xoff, const void* __restrict__ xabs,
        const void* __restrict__ h0,   const void* __restrict__ c0,
        const void* __restrict__ W_emb, const void* __restrict__ b_emb,
        const void* __restrict__ b_soc, const void* __restrict__ b_ih,
        const void* __restrict__ b_hh,  const void* __restrict__ b_out,
        const void* __restrict__ Wih_det,
        const float* __restrict__ ws, float* __restrict__ out) {
    __shared__ float xabs_s[2048];
    __shared__ int   off[2][NN_];
    __shared__ int   cnt_s[2];
    __shared__ float4 red4[2][8][16];
    __shared__ __align__(16) float xin[2][128];
    __shared__ __align__(16) float hs[2][128];
    __shared__ __align__(16) float gl[2][512];
    __shared__ __align__(16) float hnl[2][128];
    const int tid = threadIdx.x;
    const int isbf = detect_bf16(Wih_det, tid);
    const int n0 = blockIdx.x * 2;
    const unsigned short* u16 = (const unsigned short*)ws;

    for (int i = tid; i < 2048; i += 256) xabs_s[i] = ldin(xabs, i, isbf);
    if (tid < 2) cnt_s[tid] = 0;
    __syncthreads();

    const int half = tid >> 7;                     // agent 0/1 (wave-uniform)
    const int t2 = tid & 127;
    const int n = n0 + half;
    // phase A: grid_mask replica, compact valid neighbors
    {
        float xs = xabs_s[2 * n]     - 0.2f;       // x[n] - NS/2
        float ys = xabs_s[2 * n + 1] - 0.2f;
        for (int i = t2; i < NN_; i += 128) {
            float dx = xabs_s[2 * i]     - xs;
            float dy = xabs_s[2 * i + 1] - ys;
            int cx = (int)floorf(dx / 0.4f * 8.0f);
            int cy = (int)floorf(dy / 0.4f * 8.0f);
            bool valid = (dx >= 0.0f) && (dx < 0.4f) && (dy >= 0.0f) && (dy < 0.4f)
                      && (cx >= 0) && (cx < 8) && (cy >= 0) && (cy < 8) && (i != n);
            if (valid) {
                int idx = atomicAdd(&cnt_s[half], 1);
                off[half][idx] = i * 4096 + ((cy * 8 + cx) << 6);
            }
        }
    }
    __syncthreads();
    // phase B: branch-free gathers (8 streams x 16 e4-lanes per agent)
    {
        const unsigned short* P16 = (const unsigned short*)ws + U_P;
        const int strm = t2 >> 4, e4 = t2 & 15;
        const int cc = cnt_s[half];
        float ax = 0.0f, ay = 0.0f, az = 0.0f, aw = 0.0f;
        for (int j = strm; j < cc; j += 8) {
            int o = off[half][j];
            ushort4 u = *(const ushort4*)(P16 + o + 4 * e4);
            ax += b2f_(u.x); ay += b2f_(u.y); az += b2f_(u.z); aw += b2f_(u.w);
        }
        red4[half][strm][e4] = make_float4(ax, ay, az, aw);
    }
    __syncthreads();
    // xin = [emb | relu(pool + b_soc)],  hs = h0 row
    if (t2 < 16) {
        float4 s = make_float4(0.0f, 0.0f, 0.0f, 0.0f);
#pragma unroll
        for (int s8 = 0; s8 < 8; s8++) {
            float4 r = red4[half][s8][t2];
            s.x += r.x; s.y += r.y; s.z += r.z; s.w += r.w;
        }
        int e = 4 * t2;
        xin[half][64 + e]     = fmaxf(s.x + ldin(b_soc, e,     isbf), 0.0f);
        xin[half][64 + e + 1] = fmaxf(s.y + ldin(b_soc, e + 1, isbf), 0.0f);
        xin[half][64 + e + 2] = fmaxf(s.z + ldin(b_soc, e + 2, isbf), 0.0f);
        xin[half][64 + e + 3] = fmaxf(s.w + ldin(b_soc, e + 3, isbf), 0.0f);
    }
    if (t2 < 64) {
        int e = t2;
        float v = fmaf(ldin(xoff, 2 * n, isbf),     ldin(W_emb, 2 * e, isbf),
                  fmaf(ldin(xoff, 2 * n + 1, isbf), ldin(W_emb, 2 * e + 1, isbf),
                       ldin(b_emb, e, isbf)));
        xin[half][e] = fmaxf(v, 0.0f);
    }
    hs[half][t2] = ldin(h0, n * 128 + t2, isbf);
    __syncthreads();
    // gates via coalesced bf16 WT
    {
        const int j0 = 2 * tid, j1 = 2 * tid + 1;
        float ax[2] = {0, 0}, ay[2] = {0, 0};
        for (int k = 0; k < 128; k += 4) {
            union { float4 v; float f[4]; } xu[2], hu[2];
#pragma unroll
            for (int nn = 0; nn < 2; nn++) {
                xu[nn].v = *(const float4*)&xin[nn][k];
                hu[nn].v = *(const float4*)&hs[nn][k];
            }
#pragma unroll
            for (int kk = 0; kk < 4; kk++) {
                ushort2 wi = *(const ushort2*)(u16 + U_WIHT + (k + kk) * 512 + j0);
                ushort2 wh = *(const ushort2*)(u16 + U_WHHT + (k + kk) * 512 + j0);
                float wix = b2f_(wi.x), wiy = b2f_(wi.y);
                float whx = b2f_(wh.x), why = b2f_(wh.y);
#pragma unroll
                for (int nn = 0; nn < 2; nn++) {
                    float xk = xu[nn].f[kk], hk = hu[nn].f[kk];
                    ax[nn] = fmaf(xk, wix, ax[nn]); ax[nn] = fmaf(hk, whx, ax[nn]);
                    ay[nn] = fmaf(xk, wiy, ay[nn]); ay[nn] = fmaf(hk, why, ay[nn]);
                }
            }
        }
        float bb0 = ldin(b_ih, j0, isbf) + ldin(b_hh, j0, isbf);
        float bb1 = ldin(b_ih, j1, isbf) + ldin(b_hh, j1, isbf);
#pragma unroll
        for (int nn = 0; nn < 2; nn++) {
            gl[nn][j0] = ax[nn] + bb0;
            gl[nn][j1] = ay[nn] + bb1;
        }
    }
    __syncthreads();
    // LSTM pointwise
    {
        int r = t2;
        float iv = gl[half][r], fv = gl[half][r + 128];
        float gv = gl[half][r + 256], ov = gl[half][r + 384];
        float si = 1.0f / (1.0f + expf(-iv));
        float sf = 1.0f / (1.0f + expf(-fv));
        float so = 1.0f / (1.0f + expf(-ov));
        float cc = sf * ldin(c0, n * 128 + r, isbf) + si * tanhf(gv);
        hnl[half][r] = so * tanhf(cc);
    }
    __syncthreads();
    // output projection, d_out = [6][1024][20] f32
    {
        int j = t2;
        if (j < 120) {
            float acc = ldin(b_out, j, isbf);
            for (int r = 0; r < 128; r += 4) {
                float4 hq = *(const float4*)&hnl[half][r];
                acc = fmaf(hq.x, b2f_(u16[U_WOUT + (r + 0) * 128 + j]), acc);
                acc = fmaf(hq.y, b2f_(u16[U_WOUT + (r + 1) * 128 + j]), acc);
                acc = fmaf(hq.z, b2f_(u16[U_WOUT + (r + 2) * 128 + j]), acc);
                acc = fmaf(hq.w, b2f_(u16[U_WOUT + (r + 3) * 128 + j]), acc);
            }
            int ch = j / 20, wc = j - ch * 20;
            out[ch * 20480 + n * 20 + wc] = acc;
        }
    }
}

extern "C" void kernel_launch(void* const* d_in, const int* in_sizes, int n_in,
                              void* d_out, int out_size, void* d_ws, size_t ws_size,
                              hipStream_t stream) {
    const void* xoff  = d_in[0];
    const void* xabs  = d_in[1];
    const void* h0    = d_in[2];
    const void* c0    = d_in[3];
    const void* W_emb = d_in[4];
    const void* b_emb = d_in[5];
    const void* W_soc = d_in[6];
    const void* b_soc = d_in[7];
    const void* W_ih  = d_in[8];
    const void* W_hh  = d_in[9];
    const void* b_ih  = d_in[10];
    const void* b_hh  = d_in[11];
    const void* W_out = d_in[12];
    const void* b_out = d_in[13];
    float* ws = (float*)d_ws;
    float* out = (float*)d_out;

    pgemm_kernel<<<dim3(64, 16), 256, 0, stream>>>(W_soc, h0, W_ih, W_hh, W_out, ws);
    pool_lstm_kernel<<<512, 256, 0, stream>>>(xoff, xabs, h0, c0, W_emb, b_emb,
                                              b_soc, b_ih, b_hh, b_out, W_ih, ws, out);
}